// Round 17
// baseline (172.885 us; speedup 1.0000x reference)
//
#include <hip/hip_runtime.h>

// ---------------------------------------------------------------------------
// SelfAttention (distance-based, transposed accumulation), MI355X bf16 MFMA.
// B=4, S=2048, F=512, H=8, DH=64, OUT=512.
//
// ROUND 17 = ROUND 15 (154.5us best) with two changes:
//  - pass2: vt NOT LDS-staged; V B-frags loaded directly from global (L2-
//    resident via XCD swizzle), issued EARLY each iter so latency hides under
//    the score/exp phase. LDS 48->32KB (occupancy up). p_lds = r15 [128*64].
//    v is SECOND MFMA operand as a fresh per-iter register (r2-passing
//    pattern; operand rule respected).
//  - prep and packW merged into one kernel (saves a launch gap).
// Everything else BYTE-IDENTICAL to round 15.
//
// HARD RULE (r3/r4/r5/r13, 4-for-4): never issue an MFMA whose FIRST operand
// is an LDS-read fragment while the SECOND is a loop-invariant register
// fragment. Persistent fragments go in the FIRST slot only.
// ---------------------------------------------------------------------------

typedef __attribute__((ext_vector_type(8))) short bf16x8;
typedef __attribute__((ext_vector_type(4))) float f32x4;
typedef __attribute__((ext_vector_type(4))) unsigned short u16x4;

#define MFMA16 __builtin_amdgcn_mfma_f32_16x16x32_bf16
#define LOG2E 1.4426950408889634f
#define TWO_LOG2E 2.8853900817779268f

__device__ inline unsigned short f2bf(float f) {
  unsigned int u = __float_as_uint(f);
  unsigned int r = 0x7fffu + ((u >> 16) & 1u);
  return (unsigned short)((u + r) >> 16);
}
__device__ inline float bf2f(unsigned short h) {
  return __uint_as_float(((unsigned int)h) << 16);
}
__device__ inline float fexp2(float x) { return __builtin_amdgcn_exp2f(x); }

// async global->LDS, 16B per lane. lds base must be wave-uniform.
__device__ inline void gl_lds16(const unsigned short* g, unsigned short* lds) {
  __builtin_amdgcn_global_load_lds(
      (const __attribute__((address_space(1))) unsigned int*)g,
      (__attribute__((address_space(3))) unsigned int*)lds, 16, 0, 0);
}

// ---------------------------------------------------------------------------
// prep_all: blocks [0,4102): cast x to bf16 (x4) + biases.
//           blocks [4102,4358): packW LDS-tiled transpose (r15 packW body).
// ---------------------------------------------------------------------------
#define NXB4 (8192*512/4)
#define PREP_BLOCKS 4102

__global__ __launch_bounds__(256) void prep_all(
    const float* __restrict__ x, const float* __restrict__ Wq,
    const float* __restrict__ Wk, const float* __restrict__ Wv,
    const float* __restrict__ Wo, const float* __restrict__ bq,
    const float* __restrict__ bk, const float* __restrict__ bv,
    unsigned short* __restrict__ xb, unsigned short* __restrict__ wqkvT,
    unsigned short* __restrict__ woT, float* __restrict__ biasp) {
  __shared__ float tile[64][65];
  if (blockIdx.x < PREP_BLOCKS) {
    int i = blockIdx.x * blockDim.x + threadIdx.x;
    if (i < NXB4) {
      f32x4 v = ((const f32x4*)x)[i];
      u16x4 o;
      o.x = f2bf(v.x); o.y = f2bf(v.y); o.z = f2bf(v.z); o.w = f2bf(v.w);
      ((u16x4*)xb)[i] = o;
      return;
    }
    i -= NXB4;
    if (i < 1536) {
      biasp[i] = (i < 512) ? bq[i] : (i < 1024) ? bk[i - 512] : bv[i - 1024];
    }
    return;
  }
  const int bid = blockIdx.x - PREP_BLOCKS;
  const int m = bid >> 6;                 // 0..3
  const int n0 = ((bid >> 3) & 7) * 64;
  const int f0 = (bid & 7) * 64;
  const float* W = (m == 0) ? Wq : (m == 1) ? Wk : (m == 2) ? Wv : Wo;
  const int t = threadIdx.x;
  const int c = t & 63, r4 = t >> 6;             // r4 in 0..3
#pragma unroll
  for (int k = 0; k < 16; ++k) {
    const int r = r4 + k * 4;
    tile[r][c] = W[(size_t)(f0 + r) * 512 + n0 + c];   // coalesced read
  }
  __syncthreads();
#pragma unroll
  for (int k = 0; k < 16; ++k) {
    const int n_idx = r4 + k * 4, f_idx = c;
    const unsigned short v = f2bf(tile[f_idx][n_idx]); // stride-65 -> bank-free
    if (m < 3)
      wqkvT[(size_t)(m * 512 + n0 + n_idx) * 512 + f0 + f_idx] = v;  // coalesced
    else
      woT[(size_t)(n0 + n_idx) * 512 + f0 + f_idx] = v;
  }
}

// ---------------------------------------------------------------------------
// GEMM C[M,N] = A[M,K] * Bt[N,K]^T + bias. Double-buffered LDS, XCD-swizzled
// tile map (round 15 verbatim, incl. fused k2l in MODE 0).
// ---------------------------------------------------------------------------
template<int MODE>
__global__ __launch_bounds__(256) void gemm_bt(
    const unsigned short* __restrict__ A, const unsigned short* __restrict__ Bt,
    const float* __restrict__ bias,
    unsigned short* __restrict__ o_q, unsigned short* __restrict__ o_k,
    unsigned short* __restrict__ o_v, float* __restrict__ o_f,
    float* __restrict__ k2l_g, int K) {
  // T1 XCD swizzle: contiguous tile chunk per XCD (tot divisible by 8).
  const int lid = blockIdx.x + blockIdx.y * gridDim.x;
  const int tot = gridDim.x * gridDim.y;
  const int lid2 = (lid & 7) * (tot >> 3) + (lid >> 3);
  const int m0 = (lid2 / gridDim.x) * 128;
  const int n0 = (lid2 % gridDim.x) * 128;
  const int tid = threadIdx.x;
  const int w = tid >> 6, l = tid & 63, lg = l >> 4, ll = l & 15;
  const int wr = w >> 1, wc = w & 1;
  __shared__ unsigned short a_lds[2][128 * 32];
  __shared__ unsigned short b_lds[2][128 * 32];
  f32x4 acc[4][4] = {};
  const int nkt = K >> 5;
  // staging lane constants (two chunks per wave per array)
  const int cb0 = w * 64, cb1 = 256 + w * 64;
  const int cc0 = cb0 + l, cc1 = cb1 + l;
  const int ar0 = cc0 >> 2, ac0 = cc0 & 3, ar1 = cc1 >> 2, ac1 = cc1 & 3;
  // prologue: stage kt=0 into slot 0
  gl_lds16(A + (size_t)(m0 + ar0) * K + ac0 * 8, &a_lds[0][cb0 * 8]);
  gl_lds16(A + (size_t)(m0 + ar1) * K + ac1 * 8, &a_lds[0][cb1 * 8]);
  gl_lds16(Bt + (size_t)(n0 + ar0) * K + ac0 * 8, &b_lds[0][cb0 * 8]);
  gl_lds16(Bt + (size_t)(n0 + ar1) * K + ac1 * 8, &b_lds[0][cb1 * 8]);
  __syncthreads();
  for (int kt = 0; kt < nkt; ++kt) {
    const int slot = kt & 1;
    if (kt + 1 < nkt) {
      const int k1 = (kt + 1) * 32;
      gl_lds16(A + (size_t)(m0 + ar0) * K + k1 + ac0 * 8, &a_lds[slot ^ 1][cb0 * 8]);
      gl_lds16(A + (size_t)(m0 + ar1) * K + k1 + ac1 * 8, &a_lds[slot ^ 1][cb1 * 8]);
      gl_lds16(Bt + (size_t)(n0 + ar0) * K + k1 + ac0 * 8, &b_lds[slot ^ 1][cb0 * 8]);
      gl_lds16(Bt + (size_t)(n0 + ar1) * K + k1 + ac1 * 8, &b_lds[slot ^ 1][cb1 * 8]);
    }
    bf16x8 af[4], bfr[4];
#pragma unroll
    for (int mi = 0; mi < 4; ++mi)
      af[mi] = *(const bf16x8*)(&a_lds[slot][(wr * 64 + mi * 16 + ll) * 32 + lg * 8]);
#pragma unroll
    for (int ni = 0; ni < 4; ++ni)
      bfr[ni] = *(const bf16x8*)(&b_lds[slot][(wc * 64 + ni * 16 + ll) * 32 + lg * 8]);
#pragma unroll
    for (int mi = 0; mi < 4; ++mi)
#pragma unroll
      for (int ni = 0; ni < 4; ++ni)
        acc[mi][ni] = MFMA16(af[mi], bfr[ni], acc[mi][ni], 0, 0, 0);
    __syncthreads();
  }
#pragma unroll
  for (int mi = 0; mi < 4; ++mi)
#pragma unroll
    for (int ni = 0; ni < 4; ++ni) {
      const int col = n0 + wc * 64 + ni * 16 + ll;
      const float bb = bias[col];
#pragma unroll
      for (int r = 0; r < 4; ++r) {
        const int row = m0 + wr * 64 + mi * 16 + lg * 4 + r;
        float v = acc[mi][ni][r] + bb;
        if (MODE == 0) {
          const int which = col >> 9, h = (col >> 6) & 7, d = col & 63;
          const int b = row >> 11, s = row & 2047;
          if (which == 0) v *= TWO_LOG2E;  // q prescale
          const size_t idx = ((size_t)((b * 8 + h) * 2048 + s)) * 64 + d;
          (which == 0 ? o_q : which == 1 ? o_k : o_v)[idx] = f2bf(v);
        } else {
          v = v >= 0.f ? v : 0.01f * v;
          o_f[(size_t)row * 512 + col] = v;
        }
      }
    }
  // fused k2l: this wave's wc-half covers one head's full d-range (0..63)
  if (MODE == 0 && n0 >= 512 && n0 < 1024) {
    const int h = ((n0 + wc * 64) >> 6) & 7;
#pragma unroll
    for (int mi = 0; mi < 4; ++mi)
#pragma unroll
      for (int r = 0; r < 4; ++r) {
        float s2 = 0.f;
#pragma unroll
        for (int ni = 0; ni < 4; ++ni) {
          const int col = n0 + wc * 64 + ni * 16 + ll;
          const float v = acc[mi][ni][r] + bias[col];
          s2 += v * v;
        }
#pragma unroll
        for (int m = 1; m < 16; m <<= 1) s2 += __shfl_xor(s2, m);
        if (ll == 0) {
          const int row = m0 + wr * 64 + mi * 16 + lg * 4 + r;
          const int b = row >> 11, s = row & 2047;
          k2l_g[(size_t)(b * 8 + h) * 2048 + s] = LOG2E * s2;
        }
      }
  }
}

// ---------------------------------------------------------------------------
// transpose_v: vT~[bh][d][s] = invl[s] * v[bh][s][d]  (round 15 verbatim)
// ---------------------------------------------------------------------------
__global__ __launch_bounds__(256) void transpose_v(const unsigned short* __restrict__ v_g,
                                                   const float* __restrict__ invl_g,
                                                   unsigned short* __restrict__ vt_g) {
  const int bh = blockIdx.x >> 5, st = blockIdx.x & 31;
  const int s0 = st * 64;
  __shared__ unsigned short tile[64][72];
  const int t = threadIdx.x;
  {
    const int sl = t >> 2, cg = t & 3;
    const float sc = invl_g[bh * 2048 + s0 + sl];
    const unsigned short* src = v_g + ((size_t)(bh * 2048 + s0 + sl)) * 64 + cg * 16;
    bf16x8 v0 = *(const bf16x8*)(src);
    bf16x8 v1 = *(const bf16x8*)(src + 8);
#pragma unroll
    for (int e = 0; e < 8; ++e) tile[sl][cg * 16 + e] = f2bf(sc * bf2f((unsigned short)v0[e]));
#pragma unroll
    for (int e = 0; e < 8; ++e) tile[sl][cg * 16 + 8 + e] = f2bf(sc * bf2f((unsigned short)v1[e]));
  }
  __syncthreads();
  {
    const int dl = t >> 2, sg = t & 3;
    bf16x8 o0, o1;
#pragma unroll
    for (int e = 0; e < 8; ++e) o0[e] = (short)tile[sg * 16 + e][dl];
#pragma unroll
    for (int e = 0; e < 8; ++e) o1[e] = (short)tile[sg * 16 + 8 + e][dl];
    unsigned short* dst = vt_g + ((size_t)(bh * 64 + dl)) * 2048 + s0 + sg * 16;
    *(bf16x8*)dst = o0;
    *(bf16x8*)(dst + 8) = o1;
  }
}

// ---------------------------------------------------------------------------
// pass1: invl[i] = 1 / sum_j exp2(q~_i.k_j - k2l[j])  (round 15 verbatim)
// ---------------------------------------------------------------------------
__global__ __launch_bounds__(256) void pass1(const unsigned short* __restrict__ q_g,
                                             const unsigned short* __restrict__ k_g,
                                             const float* __restrict__ k2l_g,
                                             float* __restrict__ invl_g) {
  const int bx = blockIdx.x;
  const int bh = (bx & 7) * 4 + ((bx >> 3) >> 4);
  const int ib = (bx >> 3) & 15;
  const int i0 = ib * 128;
  const int tid = threadIdx.x, w = tid >> 6, l = tid & 63, lg = l >> 4, ll = l & 15;
  __shared__ unsigned short k_lds[2][64 * 64];
  __shared__ float k2_lds[2][64];
  const unsigned short* k_bh = k_g + (size_t)bh * 2048 * 64;
  const unsigned short* qrow = q_g + ((size_t)(bh * 2048 + i0 + w * 32 + ll)) * 64;
  const bf16x8 qa00 = *(const bf16x8*)(qrow + lg * 8);
  const bf16x8 qa01 = *(const bf16x8*)(qrow + 32 + lg * 8);
  const bf16x8 qa10 = *(const bf16x8*)(qrow + 1024 + lg * 8);
  const bf16x8 qa11 = *(const bf16x8*)(qrow + 1024 + 32 + lg * 8);
  float lrun0[4] = {0.f, 0.f, 0.f, 0.f};
  float lrun1[4] = {0.f, 0.f, 0.f, 0.f};
  // staging lane constants
  const int cb0 = w * 64, cb1 = 256 + w * 64;
  const int cc0 = cb0 + l, cc1 = cb1 + l;
  const int r0_ = cc0 >> 3, c0_ = cc0 & 7, r1_ = cc1 >> 3, c1_ = cc1 & 7;
  const int so0 = (c0_ ^ (r0_ & 7)) * 8;
  const int so1 = (c1_ ^ (r1_ & 7)) * 8;
  // prologue: stage jt=0 into slot 0
  gl_lds16(k_bh + (size_t)r0_ * 64 + so0, &k_lds[0][cb0 * 8]);
  gl_lds16(k_bh + (size_t)r1_ * 64 + so1, &k_lds[0][cb1 * 8]);
  if (tid < 64) k2_lds[0][tid] = k2l_g[bh * 2048 + tid];
  __syncthreads();
  for (int jt = 0; jt < 32; ++jt) {
    const int slot = jt & 1;
    if (jt + 1 < 32) {
      const int j1 = (jt + 1) * 64;
      gl_lds16(k_bh + (size_t)(j1 + r0_) * 64 + so0, &k_lds[slot ^ 1][cb0 * 8]);
      gl_lds16(k_bh + (size_t)(j1 + r1_) * 64 + so1, &k_lds[slot ^ 1][cb1 * 8]);
      if (tid < 64) k2_lds[slot ^ 1][tid] = k2l_g[bh * 2048 + j1 + tid];
    }
#pragma unroll
    for (int nf = 0; nf < 4; ++nf) {
      const int jr = nf * 16 + ll;
      const unsigned short* kb = &k_lds[slot][jr * 64];
      const int sw = jr & 7;
      bf16x8 b0 = *(const bf16x8*)(kb + ((lg ^ sw) * 8));
      bf16x8 b1 = *(const bf16x8*)(kb + (((4 + lg) ^ sw) * 8));
      f32x4 sa0 = {};
      sa0 = MFMA16(qa00, b0, sa0, 0, 0, 0);
      sa0 = MFMA16(qa01, b1, sa0, 0, 0, 0);
      f32x4 sa1 = {};
      sa1 = MFMA16(qa10, b0, sa1, 0, 0, 0);
      sa1 = MFMA16(qa11, b1, sa1, 0, 0, 0);
      const float k2v = k2_lds[slot][jr];
      lrun0[0] += fexp2(sa0[0] - k2v);
      lrun0[1] += fexp2(sa0[1] - k2v);
      lrun0[2] += fexp2(sa0[2] - k2v);
      lrun0[3] += fexp2(sa0[3] - k2v);
      lrun1[0] += fexp2(sa1[0] - k2v);
      lrun1[1] += fexp2(sa1[1] - k2v);
      lrun1[2] += fexp2(sa1[2] - k2v);
      lrun1[3] += fexp2(sa1[3] - k2v);
    }
    __syncthreads();
  }
#pragma unroll
  for (int r = 0; r < 4; ++r) {
    float t0 = lrun0[r], t1 = lrun1[r];
#pragma unroll
    for (int m = 1; m < 16; m <<= 1) { t0 += __shfl_xor(t0, m); t1 += __shfl_xor(t1, m); }
    if (ll == 0) {
      invl_g[bh * 2048 + i0 + w * 32 + lg * 4 + r] = 1.f / t0;
      invl_g[bh * 2048 + i0 + w * 32 + 16 + lg * 4 + r] = 1.f / t1;
    }
  }
}

// ---------------------------------------------------------------------------
// pass2: attn[j,d] = sum_i exp2(q~_i.k_j - k2l[j]) * v~[i,d]
// r15 structure (pack-2, q dbuf, i-split x3, XCD swizzle, p_lds[128*64],
// K-first score) EXCEPT: vt read directly from global (L2-resident), V
// B-frags loaded EARLY each iter into fresh registers (latency hides under
// score/exp). LDS 48->32KB.
// ---------------------------------------------------------------------------
__global__ __launch_bounds__(256) void pass2(const unsigned short* __restrict__ q_g,
                                             const unsigned short* __restrict__ k_g,
                                             const unsigned short* __restrict__ vt_g,
                                             const float* __restrict__ k2l_g,
                                             unsigned short* __restrict__ part0,
                                             unsigned short* __restrict__ part1,
                                             unsigned short* __restrict__ part2) {
  const int bx = blockIdx.x;
  const int bh = (bx & 7) * 4 + ((bx >> 3) >> 4);
  const int jb = (bx >> 3) & 15;
  const int by = blockIdx.y;
  const int j0 = jb * 128;
  const int it0 = by * 11;
  const int it_end = (by == 2) ? 32 : it0 + 11;
  const int tid = threadIdx.x, w = tid >> 6, l = tid & 63, lg = l >> 4, ll = l & 15;
  __shared__ unsigned short q_lds[2][64 * 64];
  __shared__ unsigned short p_lds[128 * 64];
  const unsigned short* q_base = q_g + (size_t)bh * 2048 * 64;
  const unsigned short* vt_base = vt_g + (size_t)bh * 64 * 2048;
  // K A-frags: set0 rows j0+w*32+ll, set1 rows j0+w*32+16+ll (FIRST slot)
  const unsigned short* krow = k_g + ((size_t)(bh * 2048 + j0 + w * 32 + ll)) * 64;
  const bf16x8 ka00 = *(const bf16x8*)(krow + lg * 8);
  const bf16x8 ka01 = *(const bf16x8*)(krow + 32 + lg * 8);
  const bf16x8 ka10 = *(const bf16x8*)(krow + 1024 + lg * 8);
  const bf16x8 ka11 = *(const bf16x8*)(krow + 1024 + 32 + lg * 8);
  float k2v0[4], k2v1[4];
#pragma unroll
  for (int r = 0; r < 4; ++r) {
    k2v0[r] = k2l_g[bh * 2048 + j0 + w * 32 + lg * 4 + r];
    k2v1[r] = k2l_g[bh * 2048 + j0 + w * 32 + 16 + lg * 4 + r];
  }
  // per-lane vt row base (row = nf*16+ll, columns lg*8 / 32+lg*8 of i-tile)
  const unsigned short* vrow_base = vt_base + (size_t)ll * 2048 + lg * 8;
  f32x4 oacc0[4] = {};
  f32x4 oacc1[4] = {};
  // prologue: stage q tile it0 into buf[it0&1] (keeps slot = it&1 invariant)
  const int pslot = it0 & 1;
#pragma unroll
  for (int c = 0; c < 2; ++c) {
    const int cc_base = c * 256 + w * 64;
    const int cc = cc_base + l;
    const int row = cc >> 3, cl = cc & 7;
    const int csw = (cl ^ (row & 7)) * 8;
    gl_lds16(q_base + (size_t)(it0 * 64 + row) * 64 + csw, &q_lds[pslot][cc_base * 8]);
  }
  __syncthreads();
  for (int it = it0; it < it_end; ++it) {
    const int slot = it & 1;
    if (it + 1 < it_end) {
      const int i1 = (it + 1) * 64;
#pragma unroll
      for (int c = 0; c < 2; ++c) {
        const int cc_base = c * 256 + w * 64;
        const int cc = cc_base + l;
        const int row = cc >> 3, cl = cc & 7;
        const int csw = (cl ^ (row & 7)) * 8;
        gl_lds16(q_base + (size_t)(i1 + row) * 64 + csw, &q_lds[slot ^ 1][cc_base * 8]);
      }
    }
    // EARLY V loads (global, L2-resident): fresh regs, latency hides under
    // the score/exp phase below.
    bf16x8 vfr[4][2];
#pragma unroll
    for (int nf = 0; nf < 4; ++nf) {
      const unsigned short* vr = vrow_base + (size_t)(nf * 16) * 2048 + it * 64;
      vfr[nf][0] = *(const bf16x8*)(vr);
      vfr[nf][1] = *(const bf16x8*)(vr + 32);
    }
    // scores ST[j,i] for both j-sets; P^T -> p_lds (truncating bf16 store)
#pragma unroll
    for (int nf = 0; nf < 4; ++nf) {
      const int ir = nf * 16 + ll;
      const unsigned short* qb = &q_lds[slot][ir * 64];
      const int sw = ir & 7;
      bf16x8 b0 = *(const bf16x8*)(qb + ((lg ^ sw) * 8));
      bf16x8 b1 = *(const bf16x8*)(qb + (((4 + lg) ^ sw) * 8));
      f32x4 sa0 = {};
      sa0 = MFMA16(ka00, b0, sa0, 0, 0, 0);
      sa0 = MFMA16(ka01, b1, sa0, 0, 0, 0);
      f32x4 sa1 = {};
      sa1 = MFMA16(ka10, b0, sa1, 0, 0, 0);
      sa1 = MFMA16(ka11, b1, sa1, 0, 0, 0);
#pragma unroll
      for (int r = 0; r < 4; ++r) {
        const float p0 = fexp2(sa0[r] - k2v0[r]);
        const float p1 = fexp2(sa1[r] - k2v1[r]);
        const int ja = w * 32 + lg * 4 + r;
        const int jb2 = ja + 16;
        p_lds[ja * 64 + (ir ^ ((ja & 7) << 3))] =
            (unsigned short)(__float_as_uint(p0) >> 16);
        p_lds[jb2 * 64 + (ir ^ ((jb2 & 7) << 3))] =
            (unsigned short)(__float_as_uint(p1) >> 16);
      }
    }
    // PV: A = P^T rows for both sets (within-wave LDS dependency, no barrier)
    {
      const int jr0 = w * 32 + ll;
      const int jr1 = jr0 + 16;
      const int swp = ll & 7;
      const unsigned short* pb0 = p_lds + jr0 * 64;
      const unsigned short* pb1 = p_lds + jr1 * 64;
      bf16x8 pa00 = *(const bf16x8*)(pb0 + ((lg ^ swp) * 8));
      bf16x8 pa01 = *(const bf16x8*)(pb0 + (((4 + lg) ^ swp) * 8));
      bf16x8 pa10 = *(const bf16x8*)(pb1 + ((lg ^ swp) * 8));
      bf16x8 pa11 = *(const bf16x8*)(pb1 + (((4 + lg) ^ swp) * 8));
#pragma unroll
      for (int nf = 0; nf < 4; ++nf) {
        oacc0[nf] = MFMA16(pa00, vfr[nf][0], oacc0[nf], 0, 0, 0);
        oacc0[nf] = MFMA16(pa01, vfr[nf][1], oacc0[nf], 0, 0, 0);
        oacc1[nf] = MFMA16(pa10, vfr[nf][0], oacc1[nf], 0, 0, 0);
        oacc1[nf] = MFMA16(pa11, vfr[nf][1], oacc1[nf], 0, 0, 0);
      }
    }
    __syncthreads();
  }
  unsigned short* po = (by == 0) ? part0 : (by == 1) ? part1 : part2;
  const int b = bh >> 3, h2 = bh & 7;
#pragma unroll
  for (int nf = 0; nf < 4; ++nf) {
    const int d = nf * 16 + ll;
#pragma unroll
    for (int r = 0; r < 4; ++r) {
      const int j = j0 + w * 32 + lg * 4 + r;
      po[((size_t)(b * 2048 + j)) * 512 + h2 * 64 + d] = f2bf(oacc0[nf][r]);
      po[((size_t)(b * 2048 + j + 16)) * 512 + h2 * 64 + d] = f2bf(oacc1[nf][r]);
    }
  }
}

// ---------------------------------------------------------------------------
// combine3: attnb = bf16(part0 + part1 + part2), in place over part0.
// (round 15 verbatim)
// ---------------------------------------------------------------------------
__global__ __launch_bounds__(256) void combine3(unsigned short* __restrict__ p0,
                                                const unsigned short* __restrict__ p1,
                                                const unsigned short* __restrict__ p2) {
  const int i = blockIdx.x * blockDim.x + threadIdx.x;  // ushort8 units
  bf16x8 a = ((const bf16x8*)p0)[i];
  bf16x8 b = ((const bf16x8*)p1)[i];
  bf16x8 c = ((const bf16x8*)p2)[i];
  bf16x8 o;
#pragma unroll
  for (int e = 0; e < 8; ++e)
    o[e] = (short)f2bf(bf2f((unsigned short)a[e]) + bf2f((unsigned short)b[e]) +
                       bf2f((unsigned short)c[e]));
  ((bf16x8*)p0)[i] = o;
}

// ---------------------------------------------------------------------------
extern "C" void kernel_launch(void* const* d_in, const int* in_sizes, int n_in,
                              void* d_out, int out_size, void* d_ws, size_t ws_size,
                              hipStream_t stream) {
  const float* x  = (const float*)d_in[0];
  const float* Wq = (const float*)d_in[1];
  const float* bq = (const float*)d_in[2];
  const float* Wk = (const float*)d_in[3];
  const float* bk = (const float*)d_in[4];
  const float* Wv = (const float*)d_in[5];
  const float* bv = (const float*)d_in[6];
  const float* Wo = (const float*)d_in[7];
  const float* bo = (const float*)d_in[8];
  float* out = (float*)d_out;
  char* ws = (char*)d_ws;

  unsigned short* xb    = (unsigned short*)(ws);          // also pass2 part1
  unsigned short* wqkvT = (unsigned short*)(ws + 8388608);
  unsigned short* woT   = (unsigned short*)(ws + 9961472);
  float*          biasp = (float*)         (ws + 10485760);
  unsigned short* q_g   = (unsigned short*)(ws + 10493952);
  unsigned short* k_g   = (unsigned short*)(ws + 18882560);
  unsigned short* v_g   = (unsigned short*)(ws + 27271168); // also pass2 part2
  unsigned short* vt_g  = (unsigned short*)(ws + 35659776);
  float*          k2_g  = (float*)         (ws + 44048384);
  float*          invl_g= (float*)         (ws + 44310528);
  unsigned short* attnb = (unsigned short*)(ws + 44572672); // pass2 part0
  if (ws_size < (size_t)52961280) return;

  prep_all<<<4358, 256, 0, stream>>>(x, Wq, Wk, Wv, Wo, bq, bk, bv, xb, wqkvT, woT, biasp);
  gemm_bt<0><<<dim3(12, 64), 256, 0, stream>>>(xb, wqkvT, biasp, q_g, k_g, v_g, nullptr, k2_g, 512);
  pass1<<<512, 256, 0, stream>>>(q_g, k_g, k2_g, invl_g);
  transpose_v<<<1024, 256, 0, stream>>>(v_g, invl_g, vt_g);
  pass2<<<dim3(512, 3), 256, 0, stream>>>(q_g, k_g, vt_g, k2_g, attnb, xb, v_g);
  combine3<<<2048, 256, 0, stream>>>(attnb, xb, v_g);
  gemm_bt<1><<<dim3(4, 64), 256, 0, stream>>>(attnb, woT, bo, nullptr, nullptr, nullptr, out, nullptr, 512);
}

// Round 18
// 153.710 us; speedup vs baseline: 1.1247x; 1.1247x over previous
//
#include <hip/hip_runtime.h>

// ---------------------------------------------------------------------------
// SelfAttention (distance-based, transposed accumulation), MI355X bf16 MFMA.
// B=4, S=2048, F=512, H=8, DH=64, OUT=512.
//
// ROUND 18 = ROUND 15 (154.5us, best validated) + r17's safe prep_all merge.
// pass2: r15 VERBATIM (pack-2, q/vt dbuf LDS staging, p_lds[128*64],
// i-split x3, XCD swizzle, K-first score, truncating P stores).
// r16 (p-buffer share) and r17 (v-direct) both regressed -> reverted.
//
// HARD RULE (r3/r4/r5/r13, 4-for-4): never issue an MFMA whose FIRST operand
// is an LDS-read fragment while the SECOND is a loop-invariant register
// fragment. Persistent fragments go in the FIRST slot only.
// ---------------------------------------------------------------------------

typedef __attribute__((ext_vector_type(8))) short bf16x8;
typedef __attribute__((ext_vector_type(4))) float f32x4;
typedef __attribute__((ext_vector_type(4))) unsigned short u16x4;

#define MFMA16 __builtin_amdgcn_mfma_f32_16x16x32_bf16
#define LOG2E 1.4426950408889634f
#define TWO_LOG2E 2.8853900817779268f

__device__ inline unsigned short f2bf(float f) {
  unsigned int u = __float_as_uint(f);
  unsigned int r = 0x7fffu + ((u >> 16) & 1u);
  return (unsigned short)((u + r) >> 16);
}
__device__ inline float bf2f(unsigned short h) {
  return __uint_as_float(((unsigned int)h) << 16);
}
__device__ inline float fexp2(float x) { return __builtin_amdgcn_exp2f(x); }

// async global->LDS, 16B per lane. lds base must be wave-uniform.
__device__ inline void gl_lds16(const unsigned short* g, unsigned short* lds) {
  __builtin_amdgcn_global_load_lds(
      (const __attribute__((address_space(1))) unsigned int*)g,
      (__attribute__((address_space(3))) unsigned int*)lds, 16, 0, 0);
}

// ---------------------------------------------------------------------------
// prep_all: blocks [0,4102): cast x to bf16 (x4) + biases.
//           blocks [4102,4358): packW LDS-tiled transpose.
// ---------------------------------------------------------------------------
#define NXB4 (8192*512/4)
#define PREP_BLOCKS 4102

__global__ __launch_bounds__(256) void prep_all(
    const float* __restrict__ x, const float* __restrict__ Wq,
    const float* __restrict__ Wk, const float* __restrict__ Wv,
    const float* __restrict__ Wo, const float* __restrict__ bq,
    const float* __restrict__ bk, const float* __restrict__ bv,
    unsigned short* __restrict__ xb, unsigned short* __restrict__ wqkvT,
    unsigned short* __restrict__ woT, float* __restrict__ biasp) {
  __shared__ float tile[64][65];
  if (blockIdx.x < PREP_BLOCKS) {
    int i = blockIdx.x * blockDim.x + threadIdx.x;
    if (i < NXB4) {
      f32x4 v = ((const f32x4*)x)[i];
      u16x4 o;
      o.x = f2bf(v.x); o.y = f2bf(v.y); o.z = f2bf(v.z); o.w = f2bf(v.w);
      ((u16x4*)xb)[i] = o;
      return;
    }
    i -= NXB4;
    if (i < 1536) {
      biasp[i] = (i < 512) ? bq[i] : (i < 1024) ? bk[i - 512] : bv[i - 1024];
    }
    return;
  }
  const int bid = blockIdx.x - PREP_BLOCKS;
  const int m = bid >> 6;                 // 0..3
  const int n0 = ((bid >> 3) & 7) * 64;
  const int f0 = (bid & 7) * 64;
  const float* W = (m == 0) ? Wq : (m == 1) ? Wk : (m == 2) ? Wv : Wo;
  const int t = threadIdx.x;
  const int c = t & 63, r4 = t >> 6;             // r4 in 0..3
#pragma unroll
  for (int k = 0; k < 16; ++k) {
    const int r = r4 + k * 4;
    tile[r][c] = W[(size_t)(f0 + r) * 512 + n0 + c];   // coalesced read
  }
  __syncthreads();
#pragma unroll
  for (int k = 0; k < 16; ++k) {
    const int n_idx = r4 + k * 4, f_idx = c;
    const unsigned short v = f2bf(tile[f_idx][n_idx]); // stride-65 -> bank-free
    if (m < 3)
      wqkvT[(size_t)(m * 512 + n0 + n_idx) * 512 + f0 + f_idx] = v;  // coalesced
    else
      woT[(size_t)(n0 + n_idx) * 512 + f0 + f_idx] = v;
  }
}

// ---------------------------------------------------------------------------
// GEMM C[M,N] = A[M,K] * Bt[N,K]^T + bias. Double-buffered LDS, XCD-swizzled
// tile map (round 15 verbatim, incl. fused k2l in MODE 0).
// ---------------------------------------------------------------------------
template<int MODE>
__global__ __launch_bounds__(256) void gemm_bt(
    const unsigned short* __restrict__ A, const unsigned short* __restrict__ Bt,
    const float* __restrict__ bias,
    unsigned short* __restrict__ o_q, unsigned short* __restrict__ o_k,
    unsigned short* __restrict__ o_v, float* __restrict__ o_f,
    float* __restrict__ k2l_g, int K) {
  // T1 XCD swizzle: contiguous tile chunk per XCD (tot divisible by 8).
  const int lid = blockIdx.x + blockIdx.y * gridDim.x;
  const int tot = gridDim.x * gridDim.y;
  const int lid2 = (lid & 7) * (tot >> 3) + (lid >> 3);
  const int m0 = (lid2 / gridDim.x) * 128;
  const int n0 = (lid2 % gridDim.x) * 128;
  const int tid = threadIdx.x;
  const int w = tid >> 6, l = tid & 63, lg = l >> 4, ll = l & 15;
  const int wr = w >> 1, wc = w & 1;
  __shared__ unsigned short a_lds[2][128 * 32];
  __shared__ unsigned short b_lds[2][128 * 32];
  f32x4 acc[4][4] = {};
  const int nkt = K >> 5;
  // staging lane constants (two chunks per wave per array)
  const int cb0 = w * 64, cb1 = 256 + w * 64;
  const int cc0 = cb0 + l, cc1 = cb1 + l;
  const int ar0 = cc0 >> 2, ac0 = cc0 & 3, ar1 = cc1 >> 2, ac1 = cc1 & 3;
  // prologue: stage kt=0 into slot 0
  gl_lds16(A + (size_t)(m0 + ar0) * K + ac0 * 8, &a_lds[0][cb0 * 8]);
  gl_lds16(A + (size_t)(m0 + ar1) * K + ac1 * 8, &a_lds[0][cb1 * 8]);
  gl_lds16(Bt + (size_t)(n0 + ar0) * K + ac0 * 8, &b_lds[0][cb0 * 8]);
  gl_lds16(Bt + (size_t)(n0 + ar1) * K + ac1 * 8, &b_lds[0][cb1 * 8]);
  __syncthreads();
  for (int kt = 0; kt < nkt; ++kt) {
    const int slot = kt & 1;
    if (kt + 1 < nkt) {
      const int k1 = (kt + 1) * 32;
      gl_lds16(A + (size_t)(m0 + ar0) * K + k1 + ac0 * 8, &a_lds[slot ^ 1][cb0 * 8]);
      gl_lds16(A + (size_t)(m0 + ar1) * K + k1 + ac1 * 8, &a_lds[slot ^ 1][cb1 * 8]);
      gl_lds16(Bt + (size_t)(n0 + ar0) * K + k1 + ac0 * 8, &b_lds[slot ^ 1][cb0 * 8]);
      gl_lds16(Bt + (size_t)(n0 + ar1) * K + k1 + ac1 * 8, &b_lds[slot ^ 1][cb1 * 8]);
    }
    bf16x8 af[4], bfr[4];
#pragma unroll
    for (int mi = 0; mi < 4; ++mi)
      af[mi] = *(const bf16x8*)(&a_lds[slot][(wr * 64 + mi * 16 + ll) * 32 + lg * 8]);
#pragma unroll
    for (int ni = 0; ni < 4; ++ni)
      bfr[ni] = *(const bf16x8*)(&b_lds[slot][(wc * 64 + ni * 16 + ll) * 32 + lg * 8]);
#pragma unroll
    for (int mi = 0; mi < 4; ++mi)
#pragma unroll
      for (int ni = 0; ni < 4; ++ni)
        acc[mi][ni] = MFMA16(af[mi], bfr[ni], acc[mi][ni], 0, 0, 0);
    __syncthreads();
  }
#pragma unroll
  for (int mi = 0; mi < 4; ++mi)
#pragma unroll
    for (int ni = 0; ni < 4; ++ni) {
      const int col = n0 + wc * 64 + ni * 16 + ll;
      const float bb = bias[col];
#pragma unroll
      for (int r = 0; r < 4; ++r) {
        const int row = m0 + wr * 64 + mi * 16 + lg * 4 + r;
        float v = acc[mi][ni][r] + bb;
        if (MODE == 0) {
          const int which = col >> 9, h = (col >> 6) & 7, d = col & 63;
          const int b = row >> 11, s = row & 2047;
          if (which == 0) v *= TWO_LOG2E;  // q prescale
          const size_t idx = ((size_t)((b * 8 + h) * 2048 + s)) * 64 + d;
          (which == 0 ? o_q : which == 1 ? o_k : o_v)[idx] = f2bf(v);
        } else {
          v = v >= 0.f ? v : 0.01f * v;
          o_f[(size_t)row * 512 + col] = v;
        }
      }
    }
  // fused k2l: this wave's wc-half covers one head's full d-range (0..63)
  if (MODE == 0 && n0 >= 512 && n0 < 1024) {
    const int h = ((n0 + wc * 64) >> 6) & 7;
#pragma unroll
    for (int mi = 0; mi < 4; ++mi)
#pragma unroll
      for (int r = 0; r < 4; ++r) {
        float s2 = 0.f;
#pragma unroll
        for (int ni = 0; ni < 4; ++ni) {
          const int col = n0 + wc * 64 + ni * 16 + ll;
          const float v = acc[mi][ni][r] + bias[col];
          s2 += v * v;
        }
#pragma unroll
        for (int m = 1; m < 16; m <<= 1) s2 += __shfl_xor(s2, m);
        if (ll == 0) {
          const int row = m0 + wr * 64 + mi * 16 + lg * 4 + r;
          const int b = row >> 11, s = row & 2047;
          k2l_g[(size_t)(b * 8 + h) * 2048 + s] = LOG2E * s2;
        }
      }
  }
}

// ---------------------------------------------------------------------------
// transpose_v: vT~[bh][d][s] = invl[s] * v[bh][s][d]  (round 15 verbatim)
// ---------------------------------------------------------------------------
__global__ __launch_bounds__(256) void transpose_v(const unsigned short* __restrict__ v_g,
                                                   const float* __restrict__ invl_g,
                                                   unsigned short* __restrict__ vt_g) {
  const int bh = blockIdx.x >> 5, st = blockIdx.x & 31;
  const int s0 = st * 64;
  __shared__ unsigned short tile[64][72];
  const int t = threadIdx.x;
  {
    const int sl = t >> 2, cg = t & 3;
    const float sc = invl_g[bh * 2048 + s0 + sl];
    const unsigned short* src = v_g + ((size_t)(bh * 2048 + s0 + sl)) * 64 + cg * 16;
    bf16x8 v0 = *(const bf16x8*)(src);
    bf16x8 v1 = *(const bf16x8*)(src + 8);
#pragma unroll
    for (int e = 0; e < 8; ++e) tile[sl][cg * 16 + e] = f2bf(sc * bf2f((unsigned short)v0[e]));
#pragma unroll
    for (int e = 0; e < 8; ++e) tile[sl][cg * 16 + 8 + e] = f2bf(sc * bf2f((unsigned short)v1[e]));
  }
  __syncthreads();
  {
    const int dl = t >> 2, sg = t & 3;
    bf16x8 o0, o1;
#pragma unroll
    for (int e = 0; e < 8; ++e) o0[e] = (short)tile[sg * 16 + e][dl];
#pragma unroll
    for (int e = 0; e < 8; ++e) o1[e] = (short)tile[sg * 16 + 8 + e][dl];
    unsigned short* dst = vt_g + ((size_t)(bh * 64 + dl)) * 2048 + s0 + sg * 16;
    *(bf16x8*)dst = o0;
    *(bf16x8*)(dst + 8) = o1;
  }
}

// ---------------------------------------------------------------------------
// pass1: invl[i] = 1 / sum_j exp2(q~_i.k_j - k2l[j])  (round 15 verbatim)
// ---------------------------------------------------------------------------
__global__ __launch_bounds__(256) void pass1(const unsigned short* __restrict__ q_g,
                                             const unsigned short* __restrict__ k_g,
                                             const float* __restrict__ k2l_g,
                                             float* __restrict__ invl_g) {
  const int bx = blockIdx.x;
  const int bh = (bx & 7) * 4 + ((bx >> 3) >> 4);
  const int ib = (bx >> 3) & 15;
  const int i0 = ib * 128;
  const int tid = threadIdx.x, w = tid >> 6, l = tid & 63, lg = l >> 4, ll = l & 15;
  __shared__ unsigned short k_lds[2][64 * 64];
  __shared__ float k2_lds[2][64];
  const unsigned short* k_bh = k_g + (size_t)bh * 2048 * 64;
  const unsigned short* qrow = q_g + ((size_t)(bh * 2048 + i0 + w * 32 + ll)) * 64;
  const bf16x8 qa00 = *(const bf16x8*)(qrow + lg * 8);
  const bf16x8 qa01 = *(const bf16x8*)(qrow + 32 + lg * 8);
  const bf16x8 qa10 = *(const bf16x8*)(qrow + 1024 + lg * 8);
  const bf16x8 qa11 = *(const bf16x8*)(qrow + 1024 + 32 + lg * 8);
  float lrun0[4] = {0.f, 0.f, 0.f, 0.f};
  float lrun1[4] = {0.f, 0.f, 0.f, 0.f};
  // staging lane constants
  const int cb0 = w * 64, cb1 = 256 + w * 64;
  const int cc0 = cb0 + l, cc1 = cb1 + l;
  const int r0_ = cc0 >> 3, c0_ = cc0 & 7, r1_ = cc1 >> 3, c1_ = cc1 & 7;
  const int so0 = (c0_ ^ (r0_ & 7)) * 8;
  const int so1 = (c1_ ^ (r1_ & 7)) * 8;
  // prologue: stage jt=0 into slot 0
  gl_lds16(k_bh + (size_t)r0_ * 64 + so0, &k_lds[0][cb0 * 8]);
  gl_lds16(k_bh + (size_t)r1_ * 64 + so1, &k_lds[0][cb1 * 8]);
  if (tid < 64) k2_lds[0][tid] = k2l_g[bh * 2048 + tid];
  __syncthreads();
  for (int jt = 0; jt < 32; ++jt) {
    const int slot = jt & 1;
    if (jt + 1 < 32) {
      const int j1 = (jt + 1) * 64;
      gl_lds16(k_bh + (size_t)(j1 + r0_) * 64 + so0, &k_lds[slot ^ 1][cb0 * 8]);
      gl_lds16(k_bh + (size_t)(j1 + r1_) * 64 + so1, &k_lds[slot ^ 1][cb1 * 8]);
      if (tid < 64) k2_lds[slot ^ 1][tid] = k2l_g[bh * 2048 + j1 + tid];
    }
#pragma unroll
    for (int nf = 0; nf < 4; ++nf) {
      const int jr = nf * 16 + ll;
      const unsigned short* kb = &k_lds[slot][jr * 64];
      const int sw = jr & 7;
      bf16x8 b0 = *(const bf16x8*)(kb + ((lg ^ sw) * 8));
      bf16x8 b1 = *(const bf16x8*)(kb + (((4 + lg) ^ sw) * 8));
      f32x4 sa0 = {};
      sa0 = MFMA16(qa00, b0, sa0, 0, 0, 0);
      sa0 = MFMA16(qa01, b1, sa0, 0, 0, 0);
      f32x4 sa1 = {};
      sa1 = MFMA16(qa10, b0, sa1, 0, 0, 0);
      sa1 = MFMA16(qa11, b1, sa1, 0, 0, 0);
      const float k2v = k2_lds[slot][jr];
      lrun0[0] += fexp2(sa0[0] - k2v);
      lrun0[1] += fexp2(sa0[1] - k2v);
      lrun0[2] += fexp2(sa0[2] - k2v);
      lrun0[3] += fexp2(sa0[3] - k2v);
      lrun1[0] += fexp2(sa1[0] - k2v);
      lrun1[1] += fexp2(sa1[1] - k2v);
      lrun1[2] += fexp2(sa1[2] - k2v);
      lrun1[3] += fexp2(sa1[3] - k2v);
    }
    __syncthreads();
  }
#pragma unroll
  for (int r = 0; r < 4; ++r) {
    float t0 = lrun0[r], t1 = lrun1[r];
#pragma unroll
    for (int m = 1; m < 16; m <<= 1) { t0 += __shfl_xor(t0, m); t1 += __shfl_xor(t1, m); }
    if (ll == 0) {
      invl_g[bh * 2048 + i0 + w * 32 + lg * 4 + r] = 1.f / t0;
      invl_g[bh * 2048 + i0 + w * 32 + 16 + lg * 4 + r] = 1.f / t1;
    }
  }
}

// ---------------------------------------------------------------------------
// pass2: attn[j,d] = sum_i exp2(q~_i.k_j - k2l[j]) * v~[i,d]
// ROUND 15 VERBATIM (pack-2, q/vt dbuf, i-split x3, XCD swizzle; K-first
// score, b16 truncation stores, p_lds[128*64]).
// ---------------------------------------------------------------------------
__global__ __launch_bounds__(256) void pass2(const unsigned short* __restrict__ q_g,
                                             const unsigned short* __restrict__ k_g,
                                             const unsigned short* __restrict__ vt_g,
                                             const float* __restrict__ k2l_g,
                                             unsigned short* __restrict__ part0,
                                             unsigned short* __restrict__ part1,
                                             unsigned short* __restrict__ part2) {
  const int bx = blockIdx.x;
  const int bh = (bx & 7) * 4 + ((bx >> 3) >> 4);
  const int jb = (bx >> 3) & 15;
  const int by = blockIdx.y;
  const int j0 = jb * 128;
  const int it0 = by * 11;
  const int it_end = (by == 2) ? 32 : it0 + 11;
  const int tid = threadIdx.x, w = tid >> 6, l = tid & 63, lg = l >> 4, ll = l & 15;
  __shared__ unsigned short q_lds[2][64 * 64];
  __shared__ unsigned short vt_lds[2][64 * 64];
  __shared__ unsigned short p_lds[128 * 64];
  const unsigned short* q_base = q_g + (size_t)bh * 2048 * 64;
  const unsigned short* vt_base = vt_g + (size_t)bh * 64 * 2048;
  // K A-frags: set0 rows j0+w*32+ll, set1 rows j0+w*32+16+ll (FIRST slot)
  const unsigned short* krow = k_g + ((size_t)(bh * 2048 + j0 + w * 32 + ll)) * 64;
  const bf16x8 ka00 = *(const bf16x8*)(krow + lg * 8);
  const bf16x8 ka01 = *(const bf16x8*)(krow + 32 + lg * 8);
  const bf16x8 ka10 = *(const bf16x8*)(krow + 1024 + lg * 8);
  const bf16x8 ka11 = *(const bf16x8*)(krow + 1024 + 32 + lg * 8);
  float k2v0[4], k2v1[4];
#pragma unroll
  for (int r = 0; r < 4; ++r) {
    k2v0[r] = k2l_g[bh * 2048 + j0 + w * 32 + lg * 4 + r];
    k2v1[r] = k2l_g[bh * 2048 + j0 + w * 32 + 16 + lg * 4 + r];
  }
  f32x4 oacc0[4] = {};
  f32x4 oacc1[4] = {};
  // prologue: stage tile it0 into buf[it0&1] (keeps slot = it&1 invariant)
  const int pslot = it0 & 1;
#pragma unroll
  for (int c = 0; c < 2; ++c) {
    const int cc_base = c * 256 + w * 64;
    const int cc = cc_base + l;
    const int row = cc >> 3, cl = cc & 7;
    const int csw = (cl ^ (row & 7)) * 8;
    gl_lds16(q_base + (size_t)(it0 * 64 + row) * 64 + csw, &q_lds[pslot][cc_base * 8]);
    gl_lds16(vt_base + (size_t)row * 2048 + it0 * 64 + csw, &vt_lds[pslot][cc_base * 8]);
  }
  __syncthreads();
  for (int it = it0; it < it_end; ++it) {
    const int slot = it & 1;
    if (it + 1 < it_end) {
      const int i1 = (it + 1) * 64;
#pragma unroll
      for (int c = 0; c < 2; ++c) {
        const int cc_base = c * 256 + w * 64;
        const int cc = cc_base + l;
        const int row = cc >> 3, cl = cc & 7;
        const int csw = (cl ^ (row & 7)) * 8;
        gl_lds16(q_base + (size_t)(i1 + row) * 64 + csw, &q_lds[slot ^ 1][cc_base * 8]);
        gl_lds16(vt_base + (size_t)row * 2048 + i1 + csw, &vt_lds[slot ^ 1][cc_base * 8]);
      }
    }
    // scores ST[j,i] for both j-sets; P^T -> p_lds (truncating bf16 store)
#pragma unroll
    for (int nf = 0; nf < 4; ++nf) {
      const int ir = nf * 16 + ll;
      const unsigned short* qb = &q_lds[slot][ir * 64];
      const int sw = ir & 7;
      bf16x8 b0 = *(const bf16x8*)(qb + ((lg ^ sw) * 8));
      bf16x8 b1 = *(const bf16x8*)(qb + (((4 + lg) ^ sw) * 8));
      f32x4 sa0 = {};
      sa0 = MFMA16(ka00, b0, sa0, 0, 0, 0);
      sa0 = MFMA16(ka01, b1, sa0, 0, 0, 0);
      f32x4 sa1 = {};
      sa1 = MFMA16(ka10, b0, sa1, 0, 0, 0);
      sa1 = MFMA16(ka11, b1, sa1, 0, 0, 0);
#pragma unroll
      for (int r = 0; r < 4; ++r) {
        const float p0 = fexp2(sa0[r] - k2v0[r]);
        const float p1 = fexp2(sa1[r] - k2v1[r]);
        const int ja = w * 32 + lg * 4 + r;
        const int jb2 = ja + 16;
        p_lds[ja * 64 + (ir ^ ((ja & 7) << 3))] =
            (unsigned short)(__float_as_uint(p0) >> 16);
        p_lds[jb2 * 64 + (ir ^ ((jb2 & 7) << 3))] =
            (unsigned short)(__float_as_uint(p1) >> 16);
      }
    }
    // PV: A = P^T rows for both sets (within-wave LDS dependency, no barrier)
    {
      const int jr0 = w * 32 + ll;
      const int jr1 = jr0 + 16;
      const int swp = ll & 7;
      const unsigned short* pb0 = p_lds + jr0 * 64;
      const unsigned short* pb1 = p_lds + jr1 * 64;
      bf16x8 pa00 = *(const bf16x8*)(pb0 + ((lg ^ swp) * 8));
      bf16x8 pa01 = *(const bf16x8*)(pb0 + (((4 + lg) ^ swp) * 8));
      bf16x8 pa10 = *(const bf16x8*)(pb1 + ((lg ^ swp) * 8));
      bf16x8 pa11 = *(const bf16x8*)(pb1 + (((4 + lg) ^ swp) * 8));
#pragma unroll
      for (int nf = 0; nf < 4; ++nf) {
        const int dr = nf * 16 + ll;
        const unsigned short* vb = &vt_lds[slot][dr * 64];
        const int sw = dr & 7;
        bf16x8 v0 = *(const bf16x8*)(vb + ((lg ^ sw) * 8));
        bf16x8 v1 = *(const bf16x8*)(vb + (((4 + lg) ^ sw) * 8));
        oacc0[nf] = MFMA16(pa00, v0, oacc0[nf], 0, 0, 0);
        oacc0[nf] = MFMA16(pa01, v1, oacc0[nf], 0, 0, 0);
        oacc1[nf] = MFMA16(pa10, v0, oacc1[nf], 0, 0, 0);
        oacc1[nf] = MFMA16(pa11, v1, oacc1[nf], 0, 0, 0);
      }
    }
    __syncthreads();
  }
  unsigned short* po = (by == 0) ? part0 : (by == 1) ? part1 : part2;
  const int b = bh >> 3, h2 = bh & 7;
#pragma unroll
  for (int nf = 0; nf < 4; ++nf) {
    const int d = nf * 16 + ll;
#pragma unroll
    for (int r = 0; r < 4; ++r) {
      const int j = j0 + w * 32 + lg * 4 + r;
      po[((size_t)(b * 2048 + j)) * 512 + h2 * 64 + d] = f2bf(oacc0[nf][r]);
      po[((size_t)(b * 2048 + j + 16)) * 512 + h2 * 64 + d] = f2bf(oacc1[nf][r]);
    }
  }
}

// ---------------------------------------------------------------------------
// combine3: attnb = bf16(part0 + part1 + part2), in place over part0.
// (round 15 verbatim)
// ---------------------------------------------------------------------------
__global__ __launch_bounds__(256) void combine3(unsigned short* __restrict__ p0,
                                                const unsigned short* __restrict__ p1,
                                                const unsigned short* __restrict__ p2) {
  const int i = blockIdx.x * blockDim.x + threadIdx.x;  // ushort8 units
  bf16x8 a = ((const bf16x8*)p0)[i];
  bf16x8 b = ((const bf16x8*)p1)[i];
  bf16x8 c = ((const bf16x8*)p2)[i];
  bf16x8 o;
#pragma unroll
  for (int e = 0; e < 8; ++e)
    o[e] = (short)f2bf(bf2f((unsigned short)a[e]) + bf2f((unsigned short)b[e]) +
                       bf2f((unsigned short)c[e]));
  ((bf16x8*)p0)[i] = o;
}

// ---------------------------------------------------------------------------
extern "C" void kernel_launch(void* const* d_in, const int* in_sizes, int n_in,
                              void* d_out, int out_size, void* d_ws, size_t ws_size,
                              hipStream_t stream) {
  const float* x  = (const float*)d_in[0];
  const float* Wq = (const float*)d_in[1];
  const float* bq = (const float*)d_in[2];
  const float* Wk = (const float*)d_in[3];
  const float* bk = (const float*)d_in[4];
  const float* Wv = (const float*)d_in[5];
  const float* bv = (const float*)d_in[6];
  const float* Wo = (const float*)d_in[7];
  const float* bo = (const float*)d_in[8];
  float* out = (float*)d_out;
  char* ws = (char*)d_ws;

  unsigned short* xb    = (unsigned short*)(ws);          // also pass2 part1
  unsigned short* wqkvT = (unsigned short*)(ws + 8388608);
  unsigned short* woT   = (unsigned short*)(ws + 9961472);
  float*          biasp = (float*)         (ws + 10485760);
  unsigned short* q_g   = (unsigned short*)(ws + 10493952);
  unsigned short* k_g   = (unsigned short*)(ws + 18882560);
  unsigned short* v_g   = (unsigned short*)(ws + 27271168); // also pass2 part2
  unsigned short* vt_g  = (unsigned short*)(ws + 35659776);
  float*          k2_g  = (float*)         (ws + 44048384);
  float*          invl_g= (float*)         (ws + 44310528);
  unsigned short* attnb = (unsigned short*)(ws + 44572672); // pass2 part0
  if (ws_size < (size_t)52961280) return;

  prep_all<<<4358, 256, 0, stream>>>(x, Wq, Wk, Wv, Wo, bq, bk, bv, xb, wqkvT, woT, biasp);
  gemm_bt<0><<<dim3(12, 64), 256, 0, stream>>>(xb, wqkvT, biasp, q_g, k_g, v_g, nullptr, k2_g, 512);
  pass1<<<512, 256, 0, stream>>>(q_g, k_g, k2_g, invl_g);
  transpose_v<<<1024, 256, 0, stream>>>(v_g, invl_g, vt_g);
  pass2<<<dim3(512, 3), 256, 0, stream>>>(q_g, k_g, vt_g, k2_g, attnb, xb, v_g);
  combine3<<<2048, 256, 0, stream>>>(attnb, xb, v_g);
  gemm_bt<1><<<dim3(4, 64), 256, 0, stream>>>(attnb, woT, bo, nullptr, nullptr, nullptr, out, nullptr, 512);
}

// Round 19
// 151.481 us; speedup vs baseline: 1.1413x; 1.0147x over previous
//
#include <hip/hip_runtime.h>

// ---------------------------------------------------------------------------
// SelfAttention (distance-based, transposed accumulation), MI355X bf16 MFMA.
// B=4, S=2048, F=512, H=8, DH=64, OUT=512.
//
// ROUND 19 = ROUND 18 (153.7us best) with ONE change: transpose_v fused into
// pass1's epilogue. pass1's block owns exactly the 128 i-rows whose invl it
// computes; invl published to LDS (128 floats), then the transpose_v body
// runs twice (two 64-row tiles) reusing k_lds as the tile buffer. The
// separate transpose_v kernel and the invl_g global round-trip are deleted.
// pass2 / gemms / prep_all / combine3 BYTE-IDENTICAL to round 18.
//
// HARD RULE (r3/r4/r5/r13, 4-for-4): never issue an MFMA whose FIRST operand
// is an LDS-read fragment while the SECOND is a loop-invariant register
// fragment. Persistent fragments go in the FIRST slot only.
// ---------------------------------------------------------------------------

typedef __attribute__((ext_vector_type(8))) short bf16x8;
typedef __attribute__((ext_vector_type(4))) float f32x4;
typedef __attribute__((ext_vector_type(4))) unsigned short u16x4;

#define MFMA16 __builtin_amdgcn_mfma_f32_16x16x32_bf16
#define LOG2E 1.4426950408889634f
#define TWO_LOG2E 2.8853900817779268f

__device__ inline unsigned short f2bf(float f) {
  unsigned int u = __float_as_uint(f);
  unsigned int r = 0x7fffu + ((u >> 16) & 1u);
  return (unsigned short)((u + r) >> 16);
}
__device__ inline float bf2f(unsigned short h) {
  return __uint_as_float(((unsigned int)h) << 16);
}
__device__ inline float fexp2(float x) { return __builtin_amdgcn_exp2f(x); }

// async global->LDS, 16B per lane. lds base must be wave-uniform.
__device__ inline void gl_lds16(const unsigned short* g, unsigned short* lds) {
  __builtin_amdgcn_global_load_lds(
      (const __attribute__((address_space(1))) unsigned int*)g,
      (__attribute__((address_space(3))) unsigned int*)lds, 16, 0, 0);
}

// ---------------------------------------------------------------------------
// prep_all: blocks [0,4102): cast x to bf16 (x4) + biases.
//           blocks [4102,4358): packW LDS-tiled transpose. (r18 verbatim)
// ---------------------------------------------------------------------------
#define NXB4 (8192*512/4)
#define PREP_BLOCKS 4102

__global__ __launch_bounds__(256) void prep_all(
    const float* __restrict__ x, const float* __restrict__ Wq,
    const float* __restrict__ Wk, const float* __restrict__ Wv,
    const float* __restrict__ Wo, const float* __restrict__ bq,
    const float* __restrict__ bk, const float* __restrict__ bv,
    unsigned short* __restrict__ xb, unsigned short* __restrict__ wqkvT,
    unsigned short* __restrict__ woT, float* __restrict__ biasp) {
  __shared__ float tile[64][65];
  if (blockIdx.x < PREP_BLOCKS) {
    int i = blockIdx.x * blockDim.x + threadIdx.x;
    if (i < NXB4) {
      f32x4 v = ((const f32x4*)x)[i];
      u16x4 o;
      o.x = f2bf(v.x); o.y = f2bf(v.y); o.z = f2bf(v.z); o.w = f2bf(v.w);
      ((u16x4*)xb)[i] = o;
      return;
    }
    i -= NXB4;
    if (i < 1536) {
      biasp[i] = (i < 512) ? bq[i] : (i < 1024) ? bk[i - 512] : bv[i - 1024];
    }
    return;
  }
  const int bid = blockIdx.x - PREP_BLOCKS;
  const int m = bid >> 6;                 // 0..3
  const int n0 = ((bid >> 3) & 7) * 64;
  const int f0 = (bid & 7) * 64;
  const float* W = (m == 0) ? Wq : (m == 1) ? Wk : (m == 2) ? Wv : Wo;
  const int t = threadIdx.x;
  const int c = t & 63, r4 = t >> 6;             // r4 in 0..3
#pragma unroll
  for (int k = 0; k < 16; ++k) {
    const int r = r4 + k * 4;
    tile[r][c] = W[(size_t)(f0 + r) * 512 + n0 + c];   // coalesced read
  }
  __syncthreads();
#pragma unroll
  for (int k = 0; k < 16; ++k) {
    const int n_idx = r4 + k * 4, f_idx = c;
    const unsigned short v = f2bf(tile[f_idx][n_idx]); // stride-65 -> bank-free
    if (m < 3)
      wqkvT[(size_t)(m * 512 + n0 + n_idx) * 512 + f0 + f_idx] = v;  // coalesced
    else
      woT[(size_t)(n0 + n_idx) * 512 + f0 + f_idx] = v;
  }
}

// ---------------------------------------------------------------------------
// GEMM C[M,N] = A[M,K] * Bt[N,K]^T + bias. Double-buffered LDS, XCD-swizzled
// tile map (r18 verbatim, incl. fused k2l in MODE 0).
// ---------------------------------------------------------------------------
template<int MODE>
__global__ __launch_bounds__(256) void gemm_bt(
    const unsigned short* __restrict__ A, const unsigned short* __restrict__ Bt,
    const float* __restrict__ bias,
    unsigned short* __restrict__ o_q, unsigned short* __restrict__ o_k,
    unsigned short* __restrict__ o_v, float* __restrict__ o_f,
    float* __restrict__ k2l_g, int K) {
  // T1 XCD swizzle: contiguous tile chunk per XCD (tot divisible by 8).
  const int lid = blockIdx.x + blockIdx.y * gridDim.x;
  const int tot = gridDim.x * gridDim.y;
  const int lid2 = (lid & 7) * (tot >> 3) + (lid >> 3);
  const int m0 = (lid2 / gridDim.x) * 128;
  const int n0 = (lid2 % gridDim.x) * 128;
  const int tid = threadIdx.x;
  const int w = tid >> 6, l = tid & 63, lg = l >> 4, ll = l & 15;
  const int wr = w >> 1, wc = w & 1;
  __shared__ unsigned short a_lds[2][128 * 32];
  __shared__ unsigned short b_lds[2][128 * 32];
  f32x4 acc[4][4] = {};
  const int nkt = K >> 5;
  // staging lane constants (two chunks per wave per array)
  const int cb0 = w * 64, cb1 = 256 + w * 64;
  const int cc0 = cb0 + l, cc1 = cb1 + l;
  const int ar0 = cc0 >> 2, ac0 = cc0 & 3, ar1 = cc1 >> 2, ac1 = cc1 & 3;
  // prologue: stage kt=0 into slot 0
  gl_lds16(A + (size_t)(m0 + ar0) * K + ac0 * 8, &a_lds[0][cb0 * 8]);
  gl_lds16(A + (size_t)(m0 + ar1) * K + ac1 * 8, &a_lds[0][cb1 * 8]);
  gl_lds16(Bt + (size_t)(n0 + ar0) * K + ac0 * 8, &b_lds[0][cb0 * 8]);
  gl_lds16(Bt + (size_t)(n0 + ar1) * K + ac1 * 8, &b_lds[0][cb1 * 8]);
  __syncthreads();
  for (int kt = 0; kt < nkt; ++kt) {
    const int slot = kt & 1;
    if (kt + 1 < nkt) {
      const int k1 = (kt + 1) * 32;
      gl_lds16(A + (size_t)(m0 + ar0) * K + k1 + ac0 * 8, &a_lds[slot ^ 1][cb0 * 8]);
      gl_lds16(A + (size_t)(m0 + ar1) * K + k1 + ac1 * 8, &a_lds[slot ^ 1][cb1 * 8]);
      gl_lds16(Bt + (size_t)(n0 + ar0) * K + k1 + ac0 * 8, &b_lds[slot ^ 1][cb0 * 8]);
      gl_lds16(Bt + (size_t)(n0 + ar1) * K + k1 + ac1 * 8, &b_lds[slot ^ 1][cb1 * 8]);
    }
    bf16x8 af[4], bfr[4];
#pragma unroll
    for (int mi = 0; mi < 4; ++mi)
      af[mi] = *(const bf16x8*)(&a_lds[slot][(wr * 64 + mi * 16 + ll) * 32 + lg * 8]);
#pragma unroll
    for (int ni = 0; ni < 4; ++ni)
      bfr[ni] = *(const bf16x8*)(&b_lds[slot][(wc * 64 + ni * 16 + ll) * 32 + lg * 8]);
#pragma unroll
    for (int mi = 0; mi < 4; ++mi)
#pragma unroll
      for (int ni = 0; ni < 4; ++ni)
        acc[mi][ni] = MFMA16(af[mi], bfr[ni], acc[mi][ni], 0, 0, 0);
    __syncthreads();
  }
#pragma unroll
  for (int mi = 0; mi < 4; ++mi)
#pragma unroll
    for (int ni = 0; ni < 4; ++ni) {
      const int col = n0 + wc * 64 + ni * 16 + ll;
      const float bb = bias[col];
#pragma unroll
      for (int r = 0; r < 4; ++r) {
        const int row = m0 + wr * 64 + mi * 16 + lg * 4 + r;
        float v = acc[mi][ni][r] + bb;
        if (MODE == 0) {
          const int which = col >> 9, h = (col >> 6) & 7, d = col & 63;
          const int b = row >> 11, s = row & 2047;
          if (which == 0) v *= TWO_LOG2E;  // q prescale
          const size_t idx = ((size_t)((b * 8 + h) * 2048 + s)) * 64 + d;
          (which == 0 ? o_q : which == 1 ? o_k : o_v)[idx] = f2bf(v);
        } else {
          v = v >= 0.f ? v : 0.01f * v;
          o_f[(size_t)row * 512 + col] = v;
        }
      }
    }
  // fused k2l: this wave's wc-half covers one head's full d-range (0..63)
  if (MODE == 0 && n0 >= 512 && n0 < 1024) {
    const int h = ((n0 + wc * 64) >> 6) & 7;
#pragma unroll
    for (int mi = 0; mi < 4; ++mi)
#pragma unroll
      for (int r = 0; r < 4; ++r) {
        float s2 = 0.f;
#pragma unroll
        for (int ni = 0; ni < 4; ++ni) {
          const int col = n0 + wc * 64 + ni * 16 + ll;
          const float v = acc[mi][ni][r] + bias[col];
          s2 += v * v;
        }
#pragma unroll
        for (int m = 1; m < 16; m <<= 1) s2 += __shfl_xor(s2, m);
        if (ll == 0) {
          const int row = m0 + wr * 64 + mi * 16 + lg * 4 + r;
          const int b = row >> 11, s = row & 2047;
          k2l_g[(size_t)(b * 8 + h) * 2048 + s] = LOG2E * s2;
        }
      }
  }
}

// ---------------------------------------------------------------------------
// pass1: invl[i] = 1 / sum_j exp2(q~_i.k_j - k2l[j]) FUSED with transpose_v:
// after the j-loop, invl published to LDS (128 floats), then the r18
// transpose_v body runs twice (two 64-row tiles of this block's i-range),
// scaling v by invl from LDS and writing vt. k_lds reused as tile buffer.
// Main loop body / staging / sync byte-identical to r18 pass1.
// ---------------------------------------------------------------------------
__global__ __launch_bounds__(256) void pass1(const unsigned short* __restrict__ q_g,
                                             const unsigned short* __restrict__ k_g,
                                             const float* __restrict__ k2l_g,
                                             const unsigned short* __restrict__ v_g,
                                             unsigned short* __restrict__ vt_g) {
  const int bx = blockIdx.x;
  const int bh = (bx & 7) * 4 + ((bx >> 3) >> 4);
  const int ib = (bx >> 3) & 15;
  const int i0 = ib * 128;
  const int tid = threadIdx.x, w = tid >> 6, l = tid & 63, lg = l >> 4, ll = l & 15;
  __shared__ unsigned short k_lds[2][64 * 64];
  __shared__ float k2_lds[2][64];
  __shared__ float inv_lds[128];
  const unsigned short* k_bh = k_g + (size_t)bh * 2048 * 64;
  const unsigned short* qrow = q_g + ((size_t)(bh * 2048 + i0 + w * 32 + ll)) * 64;
  const bf16x8 qa00 = *(const bf16x8*)(qrow + lg * 8);
  const bf16x8 qa01 = *(const bf16x8*)(qrow + 32 + lg * 8);
  const bf16x8 qa10 = *(const bf16x8*)(qrow + 1024 + lg * 8);
  const bf16x8 qa11 = *(const bf16x8*)(qrow + 1024 + 32 + lg * 8);
  float lrun0[4] = {0.f, 0.f, 0.f, 0.f};
  float lrun1[4] = {0.f, 0.f, 0.f, 0.f};
  // staging lane constants
  const int cb0 = w * 64, cb1 = 256 + w * 64;
  const int cc0 = cb0 + l, cc1 = cb1 + l;
  const int r0_ = cc0 >> 3, c0_ = cc0 & 7, r1_ = cc1 >> 3, c1_ = cc1 & 7;
  const int so0 = (c0_ ^ (r0_ & 7)) * 8;
  const int so1 = (c1_ ^ (r1_ & 7)) * 8;
  // prologue: stage jt=0 into slot 0
  gl_lds16(k_bh + (size_t)r0_ * 64 + so0, &k_lds[0][cb0 * 8]);
  gl_lds16(k_bh + (size_t)r1_ * 64 + so1, &k_lds[0][cb1 * 8]);
  if (tid < 64) k2_lds[0][tid] = k2l_g[bh * 2048 + tid];
  __syncthreads();
  for (int jt = 0; jt < 32; ++jt) {
    const int slot = jt & 1;
    if (jt + 1 < 32) {
      const int j1 = (jt + 1) * 64;
      gl_lds16(k_bh + (size_t)(j1 + r0_) * 64 + so0, &k_lds[slot ^ 1][cb0 * 8]);
      gl_lds16(k_bh + (size_t)(j1 + r1_) * 64 + so1, &k_lds[slot ^ 1][cb1 * 8]);
      if (tid < 64) k2_lds[slot ^ 1][tid] = k2l_g[bh * 2048 + j1 + tid];
    }
#pragma unroll
    for (int nf = 0; nf < 4; ++nf) {
      const int jr = nf * 16 + ll;
      const unsigned short* kb = &k_lds[slot][jr * 64];
      const int sw = jr & 7;
      bf16x8 b0 = *(const bf16x8*)(kb + ((lg ^ sw) * 8));
      bf16x8 b1 = *(const bf16x8*)(kb + (((4 + lg) ^ sw) * 8));
      f32x4 sa0 = {};
      sa0 = MFMA16(qa00, b0, sa0, 0, 0, 0);
      sa0 = MFMA16(qa01, b1, sa0, 0, 0, 0);
      f32x4 sa1 = {};
      sa1 = MFMA16(qa10, b0, sa1, 0, 0, 0);
      sa1 = MFMA16(qa11, b1, sa1, 0, 0, 0);
      const float k2v = k2_lds[slot][jr];
      lrun0[0] += fexp2(sa0[0] - k2v);
      lrun0[1] += fexp2(sa0[1] - k2v);
      lrun0[2] += fexp2(sa0[2] - k2v);
      lrun0[3] += fexp2(sa0[3] - k2v);
      lrun1[0] += fexp2(sa1[0] - k2v);
      lrun1[1] += fexp2(sa1[1] - k2v);
      lrun1[2] += fexp2(sa1[2] - k2v);
      lrun1[3] += fexp2(sa1[3] - k2v);
    }
    __syncthreads();
  }
  // invl -> LDS (all lanes hold the butterfly result; lane ll==0 writes)
#pragma unroll
  for (int r = 0; r < 4; ++r) {
    float t0 = lrun0[r], t1 = lrun1[r];
#pragma unroll
    for (int m = 1; m < 16; m <<= 1) { t0 += __shfl_xor(t0, m); t1 += __shfl_xor(t1, m); }
    if (ll == 0) {
      inv_lds[w * 32 + lg * 4 + r] = 1.f / t0;
      inv_lds[w * 32 + 16 + lg * 4 + r] = 1.f / t1;
    }
  }
  __syncthreads();
  // fused transpose_v (r18 body, scale from inv_lds), two 64-row tiles;
  // k_lds reused as the [64][72] tile buffer (9.2KB <= 16KB).
  unsigned short* tile = &k_lds[0][0];
#pragma unroll 1
  for (int half = 0; half < 2; ++half) {
    const int s0g = i0 + half * 64;
    {
      const int sl = tid >> 2, cg = tid & 3;
      const float sc = inv_lds[half * 64 + sl];
      const unsigned short* src = v_g + ((size_t)(bh * 2048 + s0g + sl)) * 64 + cg * 16;
      bf16x8 v0 = *(const bf16x8*)(src);
      bf16x8 v1 = *(const bf16x8*)(src + 8);
#pragma unroll
      for (int e = 0; e < 8; ++e) tile[sl * 72 + cg * 16 + e] = f2bf(sc * bf2f((unsigned short)v0[e]));
#pragma unroll
      for (int e = 0; e < 8; ++e) tile[sl * 72 + cg * 16 + 8 + e] = f2bf(sc * bf2f((unsigned short)v1[e]));
    }
    __syncthreads();
    {
      const int dl = tid >> 2, sg = tid & 3;
      bf16x8 o0, o1;
#pragma unroll
      for (int e = 0; e < 8; ++e) o0[e] = (short)tile[(sg * 16 + e) * 72 + dl];
#pragma unroll
      for (int e = 0; e < 8; ++e) o1[e] = (short)tile[(sg * 16 + 8 + e) * 72 + dl];
      unsigned short* dst = vt_g + ((size_t)(bh * 64 + dl)) * 2048 + s0g + sg * 16;
      *(bf16x8*)dst = o0;
      *(bf16x8*)(dst + 8) = o1;
    }
    __syncthreads();
  }
}

// ---------------------------------------------------------------------------
// pass2: attn[j,d] = sum_i exp2(q~_i.k_j - k2l[j]) * v~[i,d]
// ROUND 18 VERBATIM (pack-2, q/vt dbuf, i-split x3, XCD swizzle; K-first
// score, b16 truncation stores, p_lds[128*64]).
// ---------------------------------------------------------------------------
__global__ __launch_bounds__(256) void pass2(const unsigned short* __restrict__ q_g,
                                             const unsigned short* __restrict__ k_g,
                                             const unsigned short* __restrict__ vt_g,
                                             const float* __restrict__ k2l_g,
                                             unsigned short* __restrict__ part0,
                                             unsigned short* __restrict__ part1,
                                             unsigned short* __restrict__ part2) {
  const int bx = blockIdx.x;
  const int bh = (bx & 7) * 4 + ((bx >> 3) >> 4);
  const int jb = (bx >> 3) & 15;
  const int by = blockIdx.y;
  const int j0 = jb * 128;
  const int it0 = by * 11;
  const int it_end = (by == 2) ? 32 : it0 + 11;
  const int tid = threadIdx.x, w = tid >> 6, l = tid & 63, lg = l >> 4, ll = l & 15;
  __shared__ unsigned short q_lds[2][64 * 64];
  __shared__ unsigned short vt_lds[2][64 * 64];
  __shared__ unsigned short p_lds[128 * 64];
  const unsigned short* q_base = q_g + (size_t)bh * 2048 * 64;
  const unsigned short* vt_base = vt_g + (size_t)bh * 64 * 2048;
  // K A-frags: set0 rows j0+w*32+ll, set1 rows j0+w*32+16+ll (FIRST slot)
  const unsigned short* krow = k_g + ((size_t)(bh * 2048 + j0 + w * 32 + ll)) * 64;
  const bf16x8 ka00 = *(const bf16x8*)(krow + lg * 8);
  const bf16x8 ka01 = *(const bf16x8*)(krow + 32 + lg * 8);
  const bf16x8 ka10 = *(const bf16x8*)(krow + 1024 + lg * 8);
  const bf16x8 ka11 = *(const bf16x8*)(krow + 1024 + 32 + lg * 8);
  float k2v0[4], k2v1[4];
#pragma unroll
  for (int r = 0; r < 4; ++r) {
    k2v0[r] = k2l_g[bh * 2048 + j0 + w * 32 + lg * 4 + r];
    k2v1[r] = k2l_g[bh * 2048 + j0 + w * 32 + 16 + lg * 4 + r];
  }
  f32x4 oacc0[4] = {};
  f32x4 oacc1[4] = {};
  // prologue: stage tile it0 into buf[it0&1] (keeps slot = it&1 invariant)
  const int pslot = it0 & 1;
#pragma unroll
  for (int c = 0; c < 2; ++c) {
    const int cc_base = c * 256 + w * 64;
    const int cc = cc_base + l;
    const int row = cc >> 3, cl = cc & 7;
    const int csw = (cl ^ (row & 7)) * 8;
    gl_lds16(q_base + (size_t)(it0 * 64 + row) * 64 + csw, &q_lds[pslot][cc_base * 8]);
    gl_lds16(vt_base + (size_t)row * 2048 + it0 * 64 + csw, &vt_lds[pslot][cc_base * 8]);
  }
  __syncthreads();
  for (int it = it0; it < it_end; ++it) {
    const int slot = it & 1;
    if (it + 1 < it_end) {
      const int i1 = (it + 1) * 64;
#pragma unroll
      for (int c = 0; c < 2; ++c) {
        const int cc_base = c * 256 + w * 64;
        const int cc = cc_base + l;
        const int row = cc >> 3, cl = cc & 7;
        const int csw = (cl ^ (row & 7)) * 8;
        gl_lds16(q_base + (size_t)(i1 + row) * 64 + csw, &q_lds[slot ^ 1][cc_base * 8]);
        gl_lds16(vt_base + (size_t)row * 2048 + i1 + csw, &vt_lds[slot ^ 1][cc_base * 8]);
      }
    }
    // scores ST[j,i] for both j-sets; P^T -> p_lds (truncating bf16 store)
#pragma unroll
    for (int nf = 0; nf < 4; ++nf) {
      const int ir = nf * 16 + ll;
      const unsigned short* qb = &q_lds[slot][ir * 64];
      const int sw = ir & 7;
      bf16x8 b0 = *(const bf16x8*)(qb + ((lg ^ sw) * 8));
      bf16x8 b1 = *(const bf16x8*)(qb + (((4 + lg) ^ sw) * 8));
      f32x4 sa0 = {};
      sa0 = MFMA16(ka00, b0, sa0, 0, 0, 0);
      sa0 = MFMA16(ka01, b1, sa0, 0, 0, 0);
      f32x4 sa1 = {};
      sa1 = MFMA16(ka10, b0, sa1, 0, 0, 0);
      sa1 = MFMA16(ka11, b1, sa1, 0, 0, 0);
#pragma unroll
      for (int r = 0; r < 4; ++r) {
        const float p0 = fexp2(sa0[r] - k2v0[r]);
        const float p1 = fexp2(sa1[r] - k2v1[r]);
        const int ja = w * 32 + lg * 4 + r;
        const int jb2 = ja + 16;
        p_lds[ja * 64 + (ir ^ ((ja & 7) << 3))] =
            (unsigned short)(__float_as_uint(p0) >> 16);
        p_lds[jb2 * 64 + (ir ^ ((jb2 & 7) << 3))] =
            (unsigned short)(__float_as_uint(p1) >> 16);
      }
    }
    // PV: A = P^T rows for both sets (within-wave LDS dependency, no barrier)
    {
      const int jr0 = w * 32 + ll;
      const int jr1 = jr0 + 16;
      const int swp = ll & 7;
      const unsigned short* pb0 = p_lds + jr0 * 64;
      const unsigned short* pb1 = p_lds + jr1 * 64;
      bf16x8 pa00 = *(const bf16x8*)(pb0 + ((lg ^ swp) * 8));
      bf16x8 pa01 = *(const bf16x8*)(pb0 + (((4 + lg) ^ swp) * 8));
      bf16x8 pa10 = *(const bf16x8*)(pb1 + ((lg ^ swp) * 8));
      bf16x8 pa11 = *(const bf16x8*)(pb1 + (((4 + lg) ^ swp) * 8));
#pragma unroll
      for (int nf = 0; nf < 4; ++nf) {
        const int dr = nf * 16 + ll;
        const unsigned short* vb = &vt_lds[slot][dr * 64];
        const int sw = dr & 7;
        bf16x8 v0 = *(const bf16x8*)(vb + ((lg ^ sw) * 8));
        bf16x8 v1 = *(const bf16x8*)(vb + (((4 + lg) ^ sw) * 8));
        oacc0[nf] = MFMA16(pa00, v0, oacc0[nf], 0, 0, 0);
        oacc0[nf] = MFMA16(pa01, v1, oacc0[nf], 0, 0, 0);
        oacc1[nf] = MFMA16(pa10, v0, oacc1[nf], 0, 0, 0);
        oacc1[nf] = MFMA16(pa11, v1, oacc1[nf], 0, 0, 0);
      }
    }
    __syncthreads();
  }
  unsigned short* po = (by == 0) ? part0 : (by == 1) ? part1 : part2;
  const int b = bh >> 3, h2 = bh & 7;
#pragma unroll
  for (int nf = 0; nf < 4; ++nf) {
    const int d = nf * 16 + ll;
#pragma unroll
    for (int r = 0; r < 4; ++r) {
      const int j = j0 + w * 32 + lg * 4 + r;
      po[((size_t)(b * 2048 + j)) * 512 + h2 * 64 + d] = f2bf(oacc0[nf][r]);
      po[((size_t)(b * 2048 + j + 16)) * 512 + h2 * 64 + d] = f2bf(oacc1[nf][r]);
    }
  }
}

// ---------------------------------------------------------------------------
// combine3: attnb = bf16(part0 + part1 + part2), in place over part0.
// (r18 verbatim)
// ---------------------------------------------------------------------------
__global__ __launch_bounds__(256) void combine3(unsigned short* __restrict__ p0,
                                                const unsigned short* __restrict__ p1,
                                                const unsigned short* __restrict__ p2) {
  const int i = blockIdx.x * blockDim.x + threadIdx.x;  // ushort8 units
  bf16x8 a = ((const bf16x8*)p0)[i];
  bf16x8 b = ((const bf16x8*)p1)[i];
  bf16x8 c = ((const bf16x8*)p2)[i];
  bf16x8 o;
#pragma unroll
  for (int e = 0; e < 8; ++e)
    o[e] = (short)f2bf(bf2f((unsigned short)a[e]) + bf2f((unsigned short)b[e]) +
                       bf2f((unsigned short)c[e]));
  ((bf16x8*)p0)[i] = o;
}

// ---------------------------------------------------------------------------
extern "C" void kernel_launch(void* const* d_in, const int* in_sizes, int n_in,
                              void* d_out, int out_size, void* d_ws, size_t ws_size,
                              hipStream_t stream) {
  const float* x  = (const float*)d_in[0];
  const float* Wq = (const float*)d_in[1];
  const float* bq = (const float*)d_in[2];
  const float* Wk = (const float*)d_in[3];
  const float* bk = (const float*)d_in[4];
  const float* Wv = (const float*)d_in[5];
  const float* bv = (const float*)d_in[6];
  const float* Wo = (const float*)d_in[7];
  const float* bo = (const float*)d_in[8];
  float* out = (float*)d_out;
  char* ws = (char*)d_ws;

  unsigned short* xb    = (unsigned short*)(ws);          // also pass2 part1
  unsigned short* wqkvT = (unsigned short*)(ws + 8388608);
  unsigned short* woT   = (unsigned short*)(ws + 9961472);
  float*          biasp = (float*)         (ws + 10485760);
  unsigned short* q_g   = (unsigned short*)(ws + 10493952);
  unsigned short* k_g   = (unsigned short*)(ws + 18882560);
  unsigned short* v_g   = (unsigned short*)(ws + 27271168); // also pass2 part2
  unsigned short* vt_g  = (unsigned short*)(ws + 35659776);
  float*          k2_g  = (float*)         (ws + 44048384);
  unsigned short* attnb = (unsigned short*)(ws + 44572672); // pass2 part0
  if (ws_size < (size_t)52961280) return;

  prep_all<<<4358, 256, 0, stream>>>(x, Wq, Wk, Wv, Wo, bq, bk, bv, xb, wqkvT, woT, biasp);
  gemm_bt<0><<<dim3(12, 64), 256, 0, stream>>>(xb, wqkvT, biasp, q_g, k_g, v_g, nullptr, k2_g, 512);
  pass1<<<512, 256, 0, stream>>>(q_g, k_g, k2_g, v_g, vt_g);
  pass2<<<dim3(512, 3), 256, 0, stream>>>(q_g, k_g, vt_g, k2_g, attnb, xb, v_g);
  combine3<<<2048, 256, 0, stream>>>(attnb, xb, v_g);
  gemm_bt<1><<<dim3(4, 64), 256, 0, stream>>>(attnb, woT, bo, nullptr, nullptr, nullptr, out, nullptr, 512);
}

// Round 20
// 146.659 us; speedup vs baseline: 1.1788x; 1.0329x over previous
//
#include <hip/hip_runtime.h>

// ---------------------------------------------------------------------------
// SelfAttention (distance-based, transposed accumulation), MI355X bf16 MFMA.
// B=4, S=2048, F=512, H=8, DH=64, OUT=512.
//
// ROUND 20 = ROUND 19 (151.5us best) with ONE pass2 parameter change:
// 8-wave blocks (512 threads), j-tile 256 (j0=jb*256), grid (256,3).
// Per-wave loop body identical (32 j-rows, same score/P/PV code); q/vt
// staging amortized over 8 waves (1 chunk/thread); p_lds[256*64];
// LDS 64KB -> 2 blocks/CU = 16 waves/CU (was 12).
// Everything else BYTE-IDENTICAL to round 19.
//
// HARD RULE (r3/r4/r5/r13, 4-for-4): never issue an MFMA whose FIRST operand
// is an LDS-read fragment while the SECOND is a loop-invariant register
// fragment. Persistent fragments go in the FIRST slot only.
// ---------------------------------------------------------------------------

typedef __attribute__((ext_vector_type(8))) short bf16x8;
typedef __attribute__((ext_vector_type(4))) float f32x4;
typedef __attribute__((ext_vector_type(4))) unsigned short u16x4;

#define MFMA16 __builtin_amdgcn_mfma_f32_16x16x32_bf16
#define LOG2E 1.4426950408889634f
#define TWO_LOG2E 2.8853900817779268f

__device__ inline unsigned short f2bf(float f) {
  unsigned int u = __float_as_uint(f);
  unsigned int r = 0x7fffu + ((u >> 16) & 1u);
  return (unsigned short)((u + r) >> 16);
}
__device__ inline float bf2f(unsigned short h) {
  return __uint_as_float(((unsigned int)h) << 16);
}
__device__ inline float fexp2(float x) { return __builtin_amdgcn_exp2f(x); }

// async global->LDS, 16B per lane. lds base must be wave-uniform.
__device__ inline void gl_lds16(const unsigned short* g, unsigned short* lds) {
  __builtin_amdgcn_global_load_lds(
      (const __attribute__((address_space(1))) unsigned int*)g,
      (__attribute__((address_space(3))) unsigned int*)lds, 16, 0, 0);
}

// ---------------------------------------------------------------------------
// prep_all: blocks [0,4102): cast x to bf16 (x4) + biases.
//           blocks [4102,4358): packW LDS-tiled transpose. (r19 verbatim)
// ---------------------------------------------------------------------------
#define NXB4 (8192*512/4)
#define PREP_BLOCKS 4102

__global__ __launch_bounds__(256) void prep_all(
    const float* __restrict__ x, const float* __restrict__ Wq,
    const float* __restrict__ Wk, const float* __restrict__ Wv,
    const float* __restrict__ Wo, const float* __restrict__ bq,
    const float* __restrict__ bk, const float* __restrict__ bv,
    unsigned short* __restrict__ xb, unsigned short* __restrict__ wqkvT,
    unsigned short* __restrict__ woT, float* __restrict__ biasp) {
  __shared__ float tile[64][65];
  if (blockIdx.x < PREP_BLOCKS) {
    int i = blockIdx.x * blockDim.x + threadIdx.x;
    if (i < NXB4) {
      f32x4 v = ((const f32x4*)x)[i];
      u16x4 o;
      o.x = f2bf(v.x); o.y = f2bf(v.y); o.z = f2bf(v.z); o.w = f2bf(v.w);
      ((u16x4*)xb)[i] = o;
      return;
    }
    i -= NXB4;
    if (i < 1536) {
      biasp[i] = (i < 512) ? bq[i] : (i < 1024) ? bk[i - 512] : bv[i - 1024];
    }
    return;
  }
  const int bid = blockIdx.x - PREP_BLOCKS;
  const int m = bid >> 6;                 // 0..3
  const int n0 = ((bid >> 3) & 7) * 64;
  const int f0 = (bid & 7) * 64;
  const float* W = (m == 0) ? Wq : (m == 1) ? Wk : (m == 2) ? Wv : Wo;
  const int t = threadIdx.x;
  const int c = t & 63, r4 = t >> 6;             // r4 in 0..3
#pragma unroll
  for (int k = 0; k < 16; ++k) {
    const int r = r4 + k * 4;
    tile[r][c] = W[(size_t)(f0 + r) * 512 + n0 + c];   // coalesced read
  }
  __syncthreads();
#pragma unroll
  for (int k = 0; k < 16; ++k) {
    const int n_idx = r4 + k * 4, f_idx = c;
    const unsigned short v = f2bf(tile[f_idx][n_idx]); // stride-65 -> bank-free
    if (m < 3)
      wqkvT[(size_t)(m * 512 + n0 + n_idx) * 512 + f0 + f_idx] = v;  // coalesced
    else
      woT[(size_t)(n0 + n_idx) * 512 + f0 + f_idx] = v;
  }
}

// ---------------------------------------------------------------------------
// GEMM C[M,N] = A[M,K] * Bt[N,K]^T + bias. Double-buffered LDS, XCD-swizzled
// tile map (r19 verbatim, incl. fused k2l in MODE 0).
// ---------------------------------------------------------------------------
template<int MODE>
__global__ __launch_bounds__(256) void gemm_bt(
    const unsigned short* __restrict__ A, const unsigned short* __restrict__ Bt,
    const float* __restrict__ bias,
    unsigned short* __restrict__ o_q, unsigned short* __restrict__ o_k,
    unsigned short* __restrict__ o_v, float* __restrict__ o_f,
    float* __restrict__ k2l_g, int K) {
  // T1 XCD swizzle: contiguous tile chunk per XCD (tot divisible by 8).
  const int lid = blockIdx.x + blockIdx.y * gridDim.x;
  const int tot = gridDim.x * gridDim.y;
  const int lid2 = (lid & 7) * (tot >> 3) + (lid >> 3);
  const int m0 = (lid2 / gridDim.x) * 128;
  const int n0 = (lid2 % gridDim.x) * 128;
  const int tid = threadIdx.x;
  const int w = tid >> 6, l = tid & 63, lg = l >> 4, ll = l & 15;
  const int wr = w >> 1, wc = w & 1;
  __shared__ unsigned short a_lds[2][128 * 32];
  __shared__ unsigned short b_lds[2][128 * 32];
  f32x4 acc[4][4] = {};
  const int nkt = K >> 5;
  // staging lane constants (two chunks per wave per array)
  const int cb0 = w * 64, cb1 = 256 + w * 64;
  const int cc0 = cb0 + l, cc1 = cb1 + l;
  const int ar0 = cc0 >> 2, ac0 = cc0 & 3, ar1 = cc1 >> 2, ac1 = cc1 & 3;
  // prologue: stage kt=0 into slot 0
  gl_lds16(A + (size_t)(m0 + ar0) * K + ac0 * 8, &a_lds[0][cb0 * 8]);
  gl_lds16(A + (size_t)(m0 + ar1) * K + ac1 * 8, &a_lds[0][cb1 * 8]);
  gl_lds16(Bt + (size_t)(n0 + ar0) * K + ac0 * 8, &b_lds[0][cb0 * 8]);
  gl_lds16(Bt + (size_t)(n0 + ar1) * K + ac1 * 8, &b_lds[0][cb1 * 8]);
  __syncthreads();
  for (int kt = 0; kt < nkt; ++kt) {
    const int slot = kt & 1;
    if (kt + 1 < nkt) {
      const int k1 = (kt + 1) * 32;
      gl_lds16(A + (size_t)(m0 + ar0) * K + k1 + ac0 * 8, &a_lds[slot ^ 1][cb0 * 8]);
      gl_lds16(A + (size_t)(m0 + ar1) * K + k1 + ac1 * 8, &a_lds[slot ^ 1][cb1 * 8]);
      gl_lds16(Bt + (size_t)(n0 + ar0) * K + k1 + ac0 * 8, &b_lds[slot ^ 1][cb0 * 8]);
      gl_lds16(Bt + (size_t)(n0 + ar1) * K + k1 + ac1 * 8, &b_lds[slot ^ 1][cb1 * 8]);
    }
    bf16x8 af[4], bfr[4];
#pragma unroll
    for (int mi = 0; mi < 4; ++mi)
      af[mi] = *(const bf16x8*)(&a_lds[slot][(wr * 64 + mi * 16 + ll) * 32 + lg * 8]);
#pragma unroll
    for (int ni = 0; ni < 4; ++ni)
      bfr[ni] = *(const bf16x8*)(&b_lds[slot][(wc * 64 + ni * 16 + ll) * 32 + lg * 8]);
#pragma unroll
    for (int mi = 0; mi < 4; ++mi)
#pragma unroll
      for (int ni = 0; ni < 4; ++ni)
        acc[mi][ni] = MFMA16(af[mi], bfr[ni], acc[mi][ni], 0, 0, 0);
    __syncthreads();
  }
#pragma unroll
  for (int mi = 0; mi < 4; ++mi)
#pragma unroll
    for (int ni = 0; ni < 4; ++ni) {
      const int col = n0 + wc * 64 + ni * 16 + ll;
      const float bb = bias[col];
#pragma unroll
      for (int r = 0; r < 4; ++r) {
        const int row = m0 + wr * 64 + mi * 16 + lg * 4 + r;
        float v = acc[mi][ni][r] + bb;
        if (MODE == 0) {
          const int which = col >> 9, h = (col >> 6) & 7, d = col & 63;
          const int b = row >> 11, s = row & 2047;
          if (which == 0) v *= TWO_LOG2E;  // q prescale
          const size_t idx = ((size_t)((b * 8 + h) * 2048 + s)) * 64 + d;
          (which == 0 ? o_q : which == 1 ? o_k : o_v)[idx] = f2bf(v);
        } else {
          v = v >= 0.f ? v : 0.01f * v;
          o_f[(size_t)row * 512 + col] = v;
        }
      }
    }
  // fused k2l: this wave's wc-half covers one head's full d-range (0..63)
  if (MODE == 0 && n0 >= 512 && n0 < 1024) {
    const int h = ((n0 + wc * 64) >> 6) & 7;
#pragma unroll
    for (int mi = 0; mi < 4; ++mi)
#pragma unroll
      for (int r = 0; r < 4; ++r) {
        float s2 = 0.f;
#pragma unroll
        for (int ni = 0; ni < 4; ++ni) {
          const int col = n0 + wc * 64 + ni * 16 + ll;
          const float v = acc[mi][ni][r] + bias[col];
          s2 += v * v;
        }
#pragma unroll
        for (int m = 1; m < 16; m <<= 1) s2 += __shfl_xor(s2, m);
        if (ll == 0) {
          const int row = m0 + wr * 64 + mi * 16 + lg * 4 + r;
          const int b = row >> 11, s = row & 2047;
          k2l_g[(size_t)(b * 8 + h) * 2048 + s] = LOG2E * s2;
        }
      }
  }
}

// ---------------------------------------------------------------------------
// pass1: invl + fused transpose_v (round 19 verbatim).
// ---------------------------------------------------------------------------
__global__ __launch_bounds__(256) void pass1(const unsigned short* __restrict__ q_g,
                                             const unsigned short* __restrict__ k_g,
                                             const float* __restrict__ k2l_g,
                                             const unsigned short* __restrict__ v_g,
                                             unsigned short* __restrict__ vt_g) {
  const int bx = blockIdx.x;
  const int bh = (bx & 7) * 4 + ((bx >> 3) >> 4);
  const int ib = (bx >> 3) & 15;
  const int i0 = ib * 128;
  const int tid = threadIdx.x, w = tid >> 6, l = tid & 63, lg = l >> 4, ll = l & 15;
  __shared__ unsigned short k_lds[2][64 * 64];
  __shared__ float k2_lds[2][64];
  __shared__ float inv_lds[128];
  const unsigned short* k_bh = k_g + (size_t)bh * 2048 * 64;
  const unsigned short* qrow = q_g + ((size_t)(bh * 2048 + i0 + w * 32 + ll)) * 64;
  const bf16x8 qa00 = *(const bf16x8*)(qrow + lg * 8);
  const bf16x8 qa01 = *(const bf16x8*)(qrow + 32 + lg * 8);
  const bf16x8 qa10 = *(const bf16x8*)(qrow + 1024 + lg * 8);
  const bf16x8 qa11 = *(const bf16x8*)(qrow + 1024 + 32 + lg * 8);
  float lrun0[4] = {0.f, 0.f, 0.f, 0.f};
  float lrun1[4] = {0.f, 0.f, 0.f, 0.f};
  // staging lane constants
  const int cb0 = w * 64, cb1 = 256 + w * 64;
  const int cc0 = cb0 + l, cc1 = cb1 + l;
  const int r0_ = cc0 >> 3, c0_ = cc0 & 7, r1_ = cc1 >> 3, c1_ = cc1 & 7;
  const int so0 = (c0_ ^ (r0_ & 7)) * 8;
  const int so1 = (c1_ ^ (r1_ & 7)) * 8;
  // prologue: stage jt=0 into slot 0
  gl_lds16(k_bh + (size_t)r0_ * 64 + so0, &k_lds[0][cb0 * 8]);
  gl_lds16(k_bh + (size_t)r1_ * 64 + so1, &k_lds[0][cb1 * 8]);
  if (tid < 64) k2_lds[0][tid] = k2l_g[bh * 2048 + tid];
  __syncthreads();
  for (int jt = 0; jt < 32; ++jt) {
    const int slot = jt & 1;
    if (jt + 1 < 32) {
      const int j1 = (jt + 1) * 64;
      gl_lds16(k_bh + (size_t)(j1 + r0_) * 64 + so0, &k_lds[slot ^ 1][cb0 * 8]);
      gl_lds16(k_bh + (size_t)(j1 + r1_) * 64 + so1, &k_lds[slot ^ 1][cb1 * 8]);
      if (tid < 64) k2_lds[slot ^ 1][tid] = k2l_g[bh * 2048 + j1 + tid];
    }
#pragma unroll
    for (int nf = 0; nf < 4; ++nf) {
      const int jr = nf * 16 + ll;
      const unsigned short* kb = &k_lds[slot][jr * 64];
      const int sw = jr & 7;
      bf16x8 b0 = *(const bf16x8*)(kb + ((lg ^ sw) * 8));
      bf16x8 b1 = *(const bf16x8*)(kb + (((4 + lg) ^ sw) * 8));
      f32x4 sa0 = {};
      sa0 = MFMA16(qa00, b0, sa0, 0, 0, 0);
      sa0 = MFMA16(qa01, b1, sa0, 0, 0, 0);
      f32x4 sa1 = {};
      sa1 = MFMA16(qa10, b0, sa1, 0, 0, 0);
      sa1 = MFMA16(qa11, b1, sa1, 0, 0, 0);
      const float k2v = k2_lds[slot][jr];
      lrun0[0] += fexp2(sa0[0] - k2v);
      lrun0[1] += fexp2(sa0[1] - k2v);
      lrun0[2] += fexp2(sa0[2] - k2v);
      lrun0[3] += fexp2(sa0[3] - k2v);
      lrun1[0] += fexp2(sa1[0] - k2v);
      lrun1[1] += fexp2(sa1[1] - k2v);
      lrun1[2] += fexp2(sa1[2] - k2v);
      lrun1[3] += fexp2(sa1[3] - k2v);
    }
    __syncthreads();
  }
  // invl -> LDS (all lanes hold the butterfly result; lane ll==0 writes)
#pragma unroll
  for (int r = 0; r < 4; ++r) {
    float t0 = lrun0[r], t1 = lrun1[r];
#pragma unroll
    for (int m = 1; m < 16; m <<= 1) { t0 += __shfl_xor(t0, m); t1 += __shfl_xor(t1, m); }
    if (ll == 0) {
      inv_lds[w * 32 + lg * 4 + r] = 1.f / t0;
      inv_lds[w * 32 + 16 + lg * 4 + r] = 1.f / t1;
    }
  }
  __syncthreads();
  // fused transpose_v, two 64-row tiles; k_lds reused as [64][72] buffer.
  unsigned short* tile = &k_lds[0][0];
#pragma unroll 1
  for (int half = 0; half < 2; ++half) {
    const int s0g = i0 + half * 64;
    {
      const int sl = tid >> 2, cg = tid & 3;
      const float sc = inv_lds[half * 64 + sl];
      const unsigned short* src = v_g + ((size_t)(bh * 2048 + s0g + sl)) * 64 + cg * 16;
      bf16x8 v0 = *(const bf16x8*)(src);
      bf16x8 v1 = *(const bf16x8*)(src + 8);
#pragma unroll
      for (int e = 0; e < 8; ++e) tile[sl * 72 + cg * 16 + e] = f2bf(sc * bf2f((unsigned short)v0[e]));
#pragma unroll
      for (int e = 0; e < 8; ++e) tile[sl * 72 + cg * 16 + 8 + e] = f2bf(sc * bf2f((unsigned short)v1[e]));
    }
    __syncthreads();
    {
      const int dl = tid >> 2, sg = tid & 3;
      bf16x8 o0, o1;
#pragma unroll
      for (int e = 0; e < 8; ++e) o0[e] = (short)tile[(sg * 16 + e) * 72 + dl];
#pragma unroll
      for (int e = 0; e < 8; ++e) o1[e] = (short)tile[(sg * 16 + 8 + e) * 72 + dl];
      unsigned short* dst = vt_g + ((size_t)(bh * 64 + dl)) * 2048 + s0g + sg * 16;
      *(bf16x8*)dst = o0;
      *(bf16x8*)(dst + 8) = o1;
    }
    __syncthreads();
  }
}

// ---------------------------------------------------------------------------
// pass2: attn[j,d] = sum_i exp2(q~_i.k_j - k2l[j]) * v~[i,d]
// 8-WAVE variant of the r19 template: 512 threads, j-tile 256 (j0=jb*256),
// grid (256,3). Per-wave body identical; staging 1 chunk/thread;
// p_lds[256*64]; LDS 64KB -> 2 blocks/CU = 16 waves/CU.
// ---------------------------------------------------------------------------
__global__ __launch_bounds__(512) void pass2(const unsigned short* __restrict__ q_g,
                                             const unsigned short* __restrict__ k_g,
                                             const unsigned short* __restrict__ vt_g,
                                             const float* __restrict__ k2l_g,
                                             unsigned short* __restrict__ part0,
                                             unsigned short* __restrict__ part1,
                                             unsigned short* __restrict__ part2) {
  const int bx = blockIdx.x;                  // [0,256)
  const int bh = (bx & 7) * 4 + (bx >> 6);    // bijective; 4 heads per XCD
  const int jb = (bx >> 3) & 7;
  const int by = blockIdx.y;
  const int j0 = jb * 256;
  const int it0 = by * 11;
  const int it_end = (by == 2) ? 32 : it0 + 11;
  const int tid = threadIdx.x, w = tid >> 6, l = tid & 63, lg = l >> 4, ll = l & 15;
  __shared__ unsigned short q_lds[2][64 * 64];
  __shared__ unsigned short vt_lds[2][64 * 64];
  __shared__ unsigned short p_lds[256 * 64];
  const unsigned short* q_base = q_g + (size_t)bh * 2048 * 64;
  const unsigned short* vt_base = vt_g + (size_t)bh * 64 * 2048;
  // K A-frags: set0 rows j0+w*32+ll, set1 rows j0+w*32+16+ll (FIRST slot)
  const unsigned short* krow = k_g + ((size_t)(bh * 2048 + j0 + w * 32 + ll)) * 64;
  const bf16x8 ka00 = *(const bf16x8*)(krow + lg * 8);
  const bf16x8 ka01 = *(const bf16x8*)(krow + 32 + lg * 8);
  const bf16x8 ka10 = *(const bf16x8*)(krow + 1024 + lg * 8);
  const bf16x8 ka11 = *(const bf16x8*)(krow + 1024 + 32 + lg * 8);
  float k2v0[4], k2v1[4];
#pragma unroll
  for (int r = 0; r < 4; ++r) {
    k2v0[r] = k2l_g[bh * 2048 + j0 + w * 32 + lg * 4 + r];
    k2v1[r] = k2l_g[bh * 2048 + j0 + w * 32 + 16 + lg * 4 + r];
  }
  f32x4 oacc0[4] = {};
  f32x4 oacc1[4] = {};
  // staging lane constant: ONE 16B chunk per array per thread (512 chunks)
  const int cc = w * 64 + l;
  const int row = cc >> 3, cl = cc & 7;
  const int csw = (cl ^ (row & 7)) * 8;
  // prologue: stage tile it0 into buf[it0&1] (keeps slot = it&1 invariant)
  const int pslot = it0 & 1;
  gl_lds16(q_base + (size_t)(it0 * 64 + row) * 64 + csw, &q_lds[pslot][cc * 8]);
  gl_lds16(vt_base + (size_t)row * 2048 + it0 * 64 + csw, &vt_lds[pslot][cc * 8]);
  __syncthreads();
  for (int it = it0; it < it_end; ++it) {
    const int slot = it & 1;
    if (it + 1 < it_end) {
      const int i1 = (it + 1) * 64;
      gl_lds16(q_base + (size_t)(i1 + row) * 64 + csw, &q_lds[slot ^ 1][cc * 8]);
      gl_lds16(vt_base + (size_t)row * 2048 + i1 + csw, &vt_lds[slot ^ 1][cc * 8]);
    }
    // scores ST[j,i] for both j-sets; P^T -> p_lds (truncating bf16 store)
#pragma unroll
    for (int nf = 0; nf < 4; ++nf) {
      const int ir = nf * 16 + ll;
      const unsigned short* qb = &q_lds[slot][ir * 64];
      const int sw = ir & 7;
      bf16x8 b0 = *(const bf16x8*)(qb + ((lg ^ sw) * 8));
      bf16x8 b1 = *(const bf16x8*)(qb + (((4 + lg) ^ sw) * 8));
      f32x4 sa0 = {};
      sa0 = MFMA16(ka00, b0, sa0, 0, 0, 0);
      sa0 = MFMA16(ka01, b1, sa0, 0, 0, 0);
      f32x4 sa1 = {};
      sa1 = MFMA16(ka10, b0, sa1, 0, 0, 0);
      sa1 = MFMA16(ka11, b1, sa1, 0, 0, 0);
#pragma unroll
      for (int r = 0; r < 4; ++r) {
        const float p0 = fexp2(sa0[r] - k2v0[r]);
        const float p1 = fexp2(sa1[r] - k2v1[r]);
        const int ja = w * 32 + lg * 4 + r;
        const int jb2 = ja + 16;
        p_lds[ja * 64 + (ir ^ ((ja & 7) << 3))] =
            (unsigned short)(__float_as_uint(p0) >> 16);
        p_lds[jb2 * 64 + (ir ^ ((jb2 & 7) << 3))] =
            (unsigned short)(__float_as_uint(p1) >> 16);
      }
    }
    // PV: A = P^T rows for both sets (within-wave LDS dependency, no barrier)
    {
      const int jr0 = w * 32 + ll;
      const int jr1 = jr0 + 16;
      const int swp = ll & 7;
      const unsigned short* pb0 = p_lds + jr0 * 64;
      const unsigned short* pb1 = p_lds + jr1 * 64;
      bf16x8 pa00 = *(const bf16x8*)(pb0 + ((lg ^ swp) * 8));
      bf16x8 pa01 = *(const bf16x8*)(pb0 + (((4 + lg) ^ swp) * 8));
      bf16x8 pa10 = *(const bf16x8*)(pb1 + ((lg ^ swp) * 8));
      bf16x8 pa11 = *(const bf16x8*)(pb1 + (((4 + lg) ^ swp) * 8));
#pragma unroll
      for (int nf = 0; nf < 4; ++nf) {
        const int dr = nf * 16 + ll;
        const unsigned short* vb = &vt_lds[slot][dr * 64];
        const int sw = dr & 7;
        bf16x8 v0 = *(const bf16x8*)(vb + ((lg ^ sw) * 8));
        bf16x8 v1 = *(const bf16x8*)(vb + (((4 + lg) ^ sw) * 8));
        oacc0[nf] = MFMA16(pa00, v0, oacc0[nf], 0, 0, 0);
        oacc0[nf] = MFMA16(pa01, v1, oacc0[nf], 0, 0, 0);
        oacc1[nf] = MFMA16(pa10, v0, oacc1[nf], 0, 0, 0);
        oacc1[nf] = MFMA16(pa11, v1, oacc1[nf], 0, 0, 0);
      }
    }
    __syncthreads();
  }
  unsigned short* po = (by == 0) ? part0 : (by == 1) ? part1 : part2;
  const int b = bh >> 3, h2 = bh & 7;
#pragma unroll
  for (int nf = 0; nf < 4; ++nf) {
    const int d = nf * 16 + ll;
#pragma unroll
    for (int r = 0; r < 4; ++r) {
      const int j = j0 + w * 32 + lg * 4 + r;
      po[((size_t)(b * 2048 + j)) * 512 + h2 * 64 + d] = f2bf(oacc0[nf][r]);
      po[((size_t)(b * 2048 + j + 16)) * 512 + h2 * 64 + d] = f2bf(oacc1[nf][r]);
    }
  }
}

// ---------------------------------------------------------------------------
// combine3: attnb = bf16(part0 + part1 + part2), in place over part0.
// (r19 verbatim)
// ---------------------------------------------------------------------------
__global__ __launch_bounds__(256) void combine3(unsigned short* __restrict__ p0,
                                                const unsigned short* __restrict__ p1,
                                                const unsigned short* __restrict__ p2) {
  const int i = blockIdx.x * blockDim.x + threadIdx.x;  // ushort8 units
  bf16x8 a = ((const bf16x8*)p0)[i];
  bf16x8 b = ((const bf16x8*)p1)[i];
  bf16x8 c = ((const bf16x8*)p2)[i];
  bf16x8 o;
#pragma unroll
  for (int e = 0; e < 8; ++e)
    o[e] = (short)f2bf(bf2f((unsigned short)a[e]) + bf2f((unsigned short)b[e]) +
                       bf2f((unsigned short)c[e]));
  ((bf16x8*)p0)[i] = o;
}

// ---------------------------------------------------------------------------
extern "C" void kernel_launch(void* const* d_in, const int* in_sizes, int n_in,
                              void* d_out, int out_size, void* d_ws, size_t ws_size,
                              hipStream_t stream) {
  const float* x  = (const float*)d_in[0];
  const float* Wq = (const float*)d_in[1];
  const float* bq = (const float*)d_in[2];
  const float* Wk = (const float*)d_in[3];
  const float* bk = (const float*)d_in[4];
  const float* Wv = (const float*)d_in[5];
  const float* bv = (const float*)d_in[6];
  const float* Wo = (const float*)d_in[7];
  const float* bo = (const float*)d_in[8];
  float* out = (float*)d_out;
  char* ws = (char*)d_ws;

  unsigned short* xb    = (unsigned short*)(ws);          // also pass2 part1
  unsigned short* wqkvT = (unsigned short*)(ws + 8388608);
  unsigned short* woT   = (unsigned short*)(ws + 9961472);
  float*          biasp = (float*)         (ws + 10485760);
  unsigned short* q_g   = (unsigned short*)(ws + 10493952);
  unsigned short* k_g   = (unsigned short*)(ws + 18882560);
  unsigned short* v_g   = (unsigned short*)(ws + 27271168); // also pass2 part2
  unsigned short* vt_g  = (unsigned short*)(ws + 35659776);
  float*          k2_g  = (float*)         (ws + 44048384);
  unsigned short* attnb = (unsigned short*)(ws + 44572672); // pass2 part0
  if (ws_size < (size_t)52961280) return;

  prep_all<<<4358, 256, 0, stream>>>(x, Wq, Wk, Wv, Wo, bq, bk, bv, xb, wqkvT, woT, biasp);
  gemm_bt<0><<<dim3(12, 64), 256, 0, stream>>>(xb, wqkvT, biasp, q_g, k_g, v_g, nullptr, k2_g, 512);
  pass1<<<512, 256, 0, stream>>>(q_g, k_g, k2_g, v_g, vt_g);
  pass2<<<dim3(256, 3), 512, 0, stream>>>(q_g, k_g, vt_g, k2_g, attnb, xb, v_g);
  combine3<<<2048, 256, 0, stream>>>(attnb, xb, v_g);
  gemm_bt<1><<<dim3(4, 64), 256, 0, stream>>>(attnb, woT, bo, nullptr, nullptr, nullptr, out, nullptr, 512);
}